// Round 4
// baseline (1259.512 us; speedup 1.0000x reference)
//
#include <hip/hip_runtime.h>

#define NODES 25088
#define NB 8
#define NPB 3136   // nodes per batch (56*56)
#define C 96
#define KNN 9
#define COUT 192
#define MSPLIT 8   // m-range split for knn occupancy

// ---------------- transpose x [B,C,N] -> xf [B*N, C] ----------------
__global__ void transpose_kernel(const float* __restrict__ x, float* __restrict__ xf) {
  __shared__ float t[32][33];
  int b = blockIdx.z, ct = blockIdx.y, nt = blockIdx.x;
  int tx = threadIdx.x, ty = threadIdx.y;
  int n0 = nt * 32, c0 = ct * 32;
  const float* xb = x + (size_t)b * C * NPB;
#pragma unroll
  for (int i = 0; i < 4; i++) {
    int c = c0 + ty + i * 8;
    t[ty + i * 8][tx] = xb[(size_t)c * NPB + n0 + tx];
  }
  __syncthreads();
  float* xfb = xf + (size_t)b * NPB * C;
#pragma unroll
  for (int i = 0; i < 4; i++) {
    int n = n0 + ty + i * 8;
    xfb[(size_t)n * C + c0 + tx] = t[tx][ty + i * 8];
  }
}

// ---------------- per-node squared norm ----------------
__global__ void sq_kernel(const float* __restrict__ xf, float* __restrict__ sq) {
  int node = blockIdx.x * 256 + threadIdx.x;
  const float4* r = (const float4*)(xf + (size_t)node * C);
  float s = 0.f;
#pragma unroll
  for (int i = 0; i < 24; i++) {
    float4 v = r[i];
    s += v.x * v.x + v.y * v.y + v.z * v.z + v.w * v.w;
  }
  sq[node] = s;
}

// ---------------- kNN partial: top-9 over an m-chunk ----------------
// grid (49, 8, MSPLIT), block 256 (4 waves). Block: 64 queries x one m-chunk.
// Inner loop identical to the R2 hardware-verified version; only the tile
// range (t0..t1) and the partial write-out differ.
__global__ __launch_bounds__(256) void knn_kernel(const float* __restrict__ xf,
                                                  const float* __restrict__ sq,
                                                  float* __restrict__ pk_d,
                                                  int* __restrict__ pk_i) {
  __shared__ float tile[64 * C];  // 24576 B
  __shared__ float sqs[64];
  int b = blockIdx.y;
  int z = blockIdx.z;
  int lane = threadIdx.x & 63;
  int sub = threadIdx.x >> 6;
  int row = blockIdx.x * 64 + lane;
  int bbase = b * NPB;
  int t0 = (z * 49) / MSPLIT, t1 = ((z + 1) * 49) / MSPLIT;

  float4 r4[24];
  const float4* rp = (const float4*)(xf + (size_t)(bbase + row) * C);
#pragma unroll
  for (int i = 0; i < 24; i++) r4[i] = rp[i];
  float sqr = sq[bbase + row];

  float nd[KNN];
  int ni[KNN];
#pragma unroll
  for (int q = 0; q < KNN; q++) { nd[q] = 3.4e38f; ni[q] = 0x7fffffff; }

  for (int t = t0; t < t1; t++) {
    int m0 = t * 64;
    __syncthreads();
    for (int f = threadIdx.x; f < 64 * 24; f += 256) {
      int mr = f / 24, c4 = f % 24;
      ((float4*)tile)[mr * 24 + c4] =
          ((const float4*)(xf + (size_t)(bbase + m0 + mr) * C))[c4];
    }
    if (threadIdx.x < 64) sqs[threadIdx.x] = sq[bbase + m0 + threadIdx.x];
    __syncthreads();
    for (int q = 0; q < 16; q++) {
      int mr = sub * 16 + q;
      const float4* mp = (const float4*)(tile + mr * C);
      float d0 = 0.f, d1 = 0.f, d2 = 0.f, d3 = 0.f;
#pragma unroll
      for (int i = 0; i < 24; i++) {
        float4 mv = mp[i];
        d0 += r4[i].x * mv.x;
        d1 += r4[i].y * mv.y;
        d2 += r4[i].z * mv.z;
        d3 += r4[i].w * mv.w;
      }
      float dot = (d0 + d1) + (d2 + d3);
      float d = (sqr - 2.0f * dot) + sqs[mr];
      int m = m0 + mr;
      if (d < nd[KNN - 1]) {
        nd[KNN - 1] = d;
        ni[KNN - 1] = m;
#pragma unroll
        for (int qq = KNN - 1; qq > 0; --qq) {
          if (nd[qq] < nd[qq - 1]) {
            float td = nd[qq]; nd[qq] = nd[qq - 1]; nd[qq - 1] = td;
            int ti = ni[qq]; ni[qq] = ni[qq - 1]; ni[qq - 1] = ti;
          }
        }
      }
    }
  }

  // in-block merge of the 4 sub-wave partials (lexicographic on (d, idx))
  __syncthreads();
  float* cd = tile;                       // 4*64*9 floats
  int* ci = (int*)(tile + 4 * 64 * KNN);  // 4*64*9 ints
#pragma unroll
  for (int q = 0; q < KNN; q++) {
    cd[(sub * 64 + lane) * KNN + q] = nd[q];
    ci[(sub * 64 + lane) * KNN + q] = ni[q];
  }
  __syncthreads();
  if (sub == 0) {
    float fd[KNN];
    int fi[KNN];
#pragma unroll
    for (int q = 0; q < KNN; q++) { fd[q] = 3.4e38f; fi[q] = 0x7fffffff; }
    for (int s = 0; s < 4; s++) {
#pragma unroll
      for (int q = 0; q < KNN; q++) {
        float d = cd[(s * 64 + lane) * KNN + q];
        int m = ci[(s * 64 + lane) * KNN + q];
        if (d < fd[KNN - 1] || (d == fd[KNN - 1] && m < fi[KNN - 1])) {
          fd[KNN - 1] = d;
          fi[KNN - 1] = m;
#pragma unroll
          for (int qq = KNN - 1; qq > 0; --qq) {
            bool sw = (fd[qq] < fd[qq - 1]) ||
                      (fd[qq] == fd[qq - 1] && fi[qq] < fi[qq - 1]);
            if (sw) {
              float td = fd[qq]; fd[qq] = fd[qq - 1]; fd[qq - 1] = td;
              int ti = fi[qq]; fi[qq] = fi[qq - 1]; fi[qq - 1] = ti;
            }
          }
        }
      }
    }
    size_t base = ((size_t)(bbase + row) * MSPLIT + z) * KNN;
#pragma unroll
    for (int q = 0; q < KNN; q++) {
      pk_d[base + q] = fd[q];
      pk_i[base + q] = bbase + fi[q];  // global node index
    }
  }
}

// ---------------- merge MSPLIT partial top-9 lists per query ----------------
__global__ void knn_merge_kernel(const float* __restrict__ pk_d,
                                 const int* __restrict__ pk_i,
                                 int* __restrict__ nn) {
  int q = blockIdx.x * 256 + threadIdx.x;
  float fd[KNN];
  int fi[KNN];
#pragma unroll
  for (int k = 0; k < KNN; k++) { fd[k] = 3.4e38f; fi[k] = 0x7fffffff; }
  size_t base = (size_t)q * MSPLIT * KNN;
  for (int e = 0; e < MSPLIT * KNN; e++) {
    float d = pk_d[base + e];
    int m = pk_i[base + e];
    if (d < fd[KNN - 1] || (d == fd[KNN - 1] && m < fi[KNN - 1])) {
      fd[KNN - 1] = d;
      fi[KNN - 1] = m;
#pragma unroll
      for (int qq = KNN - 1; qq > 0; --qq) {
        bool sw = (fd[qq] < fd[qq - 1]) ||
                  (fd[qq] == fd[qq - 1] && fi[qq] < fi[qq - 1]);
        if (sw) {
          float td = fd[qq]; fd[qq] = fd[qq - 1]; fd[qq - 1] = td;
          int ti = fi[qq]; fi[qq] = fi[qq - 1]; fi[qq - 1] = ti;
        }
      }
    }
  }
#pragma unroll
  for (int k = 0; k < KNN; k++) nn[(size_t)q * KNN + k] = fi[k];
}

// ---------------- fused VAE tail: hK[500] -> 64 -> 32 -> 9 -> argmax ----------------
__global__ void vae_tail_kernel(const float* __restrict__ hK,
                                const float* __restrict__ kfc_w, const float* __restrict__ kfc_b,
                                const float* __restrict__ kmu_w, const float* __restrict__ kmu_b,
                                const float* __restrict__ kdec_w, const float* __restrict__ kdec_b,
                                int node_base, int* __restrict__ kint, float* __restrict__ rs) {
  __shared__ float hrow[8][500];
  __shared__ float h64s[8][64];
  __shared__ float mus[8][32];
  __shared__ float lg[8][9];
  int tid = threadIdx.x;
  int nb = blockIdx.x * 8;
  for (int f = tid; f < 8 * 500; f += 256) {
    int nl = f / 500, q = f % 500;
    hrow[nl][q] = hK[(size_t)(nb + nl) * 500 + q];
  }
  __syncthreads();
  {
    int nl0 = tid >> 6, j = tid & 63;
    float a0 = 0.f, a1 = 0.f;
    for (int q = 0; q < 500; q++) {
      float w = kfc_w[q * 64 + j];
      a0 += hrow[nl0][q] * w;
      a1 += hrow[nl0 + 4][q] * w;
    }
    float bj = kfc_b[j];
    h64s[nl0][j] = fmaxf(a0 + bj, 0.f);
    h64s[nl0 + 4][j] = fmaxf(a1 + bj, 0.f);
  }
  __syncthreads();
  {
    int nl = tid / 32, j = tid % 32;
    float a = 0.f;
#pragma unroll
    for (int q = 0; q < 64; q++) a += h64s[nl][q] * kmu_w[q * 32 + j];
    mus[nl][j] = a + kmu_b[j];
  }
  __syncthreads();
  if (tid < 72) {
    int nl = tid / 9, j = tid % 9;
    float a = 0.f;
#pragma unroll
    for (int q = 0; q < 32; q++) a += mus[nl][q] * kdec_w[q * 9 + j];
    lg[nl][j] = a + kdec_b[j];
  }
  __syncthreads();
  if (tid < 8) {
    float best = lg[tid][0];
    int bi = 0;
#pragma unroll
    for (int j = 1; j < 9; j++) {
      if (lg[tid][j] > best) { best = lg[tid][j]; bi = j; }
    }
    kint[node_base + nb + tid] = bi;
    rs[node_base + nb + tid] = (float)bi;
  }
}

// ---------------- gather-sum of kept neighbors ----------------
__global__ void gather_kernel(const float* __restrict__ feat, const int* __restrict__ nn,
                              const int* __restrict__ kint, float* __restrict__ out) {
  int idx = blockIdx.x * 256 + threadIdx.x;
  int node = idx / 24, c4 = idx % 24;
  int kc = kint[node];
  const int* nr = nn + (size_t)node * KNN;
  float4 acc = make_float4(0.f, 0.f, 0.f, 0.f);
  for (int k = 0; k < kc; k++) {
    int j = nr[k];
    float4 v = ((const float4*)(feat + (size_t)j * C))[c4];
    acc.x += v.x; acc.y += v.y; acc.z += v.z; acc.w += v.w;
  }
  ((float4*)(out + (size_t)node * C))[c4] = acc;
}

// ---------------- generic fp32 GEMM ----------------
// C[M,N] = [A0 (rowscale sc0) | A1 (rowscale sc1)] @ B' + bscale*bias, opt relu,
// opt transpose-store to [B, COUT, NPB]. bmode 1: B' rows k<96 are B[k]-B[k+96].
__global__ __launch_bounds__(256) void gemm_kernel(
    const float* __restrict__ A0, const float* __restrict__ A1, int K0, int Ktot,
    const float* __restrict__ sc0, const float* __restrict__ sc1,
    const float* __restrict__ B, int ldb, int bmode,
    const float* __restrict__ bias, const float* __restrict__ bscale,
    float* __restrict__ Cc, int M, int N, int relu, int tstore) {
  __shared__ float As[16][68];
  __shared__ float Bs[16][68];
  int tid = threadIdx.x;
  int tx = tid & 15, ty = tid >> 4;
  int row0 = blockIdx.x * 64, col0 = blockIdx.y * 64;
  float acc[4][4] = {};
  int ai = tid >> 2;          // 0..63
  int ak = (tid & 3) * 4;     // 0,4,8,12
  int bk = tid >> 4;          // 0..15
  int bj = (tid & 15) * 4;    // 0..60
  bool edge = (col0 + 64 > N);

  for (int k0 = 0; k0 < Ktot; k0 += 16) {
    // stage A (64 x 16), transposed into As[k][i]
    {
      const float* Ap;
      const float* sc;
      int lda, kk;
      if (k0 < K0) { Ap = A0; lda = K0; sc = sc0; kk = k0; }
      else { Ap = A1; lda = Ktot - K0; sc = sc1; kk = k0 - K0; }
      int r = row0 + ai;
      float4 v = *(const float4*)(Ap + (size_t)r * lda + kk + ak);
      if (sc) { float s = sc[r]; v.x *= s; v.y *= s; v.z *= s; v.w *= s; }
      As[ak + 0][ai] = v.x;
      As[ak + 1][ai] = v.y;
      As[ak + 2][ai] = v.z;
      As[ak + 3][ai] = v.w;
    }
    // stage B (16 x 64)
    {
      int kg = k0 + bk;
      int j = col0 + bj;
      float4 v;
      if (!edge) {
        v = *(const float4*)(B + (size_t)kg * ldb + j);
        if (bmode == 1 && kg < 96) {
          float4 w = *(const float4*)(B + (size_t)(kg + 96) * ldb + j);
          v.x -= w.x; v.y -= w.y; v.z -= w.z; v.w -= w.w;
        }
      } else {
        float tmp[4];
#pragma unroll
        for (int e = 0; e < 4; e++) {
          int jj = j + e;
          float val = 0.f;
          if (jj < N) {
            val = B[(size_t)kg * ldb + jj];
            if (bmode == 1 && kg < 96) val -= B[(size_t)(kg + 96) * ldb + jj];
          }
          tmp[e] = val;
        }
        v = make_float4(tmp[0], tmp[1], tmp[2], tmp[3]);
      }
      *(float4*)&Bs[bk][bj] = v;
    }
    __syncthreads();
#pragma unroll
    for (int kk = 0; kk < 16; kk++) {
      float4 av = *(const float4*)&As[kk][ty * 4];
      float4 bv = *(const float4*)&Bs[kk][tx * 4];
      acc[0][0] += av.x * bv.x; acc[0][1] += av.x * bv.y; acc[0][2] += av.x * bv.z; acc[0][3] += av.x * bv.w;
      acc[1][0] += av.y * bv.x; acc[1][1] += av.y * bv.y; acc[1][2] += av.y * bv.z; acc[1][3] += av.y * bv.w;
      acc[2][0] += av.z * bv.x; acc[2][1] += av.z * bv.y; acc[2][2] += av.z * bv.z; acc[2][3] += av.z * bv.w;
      acc[3][0] += av.w * bv.x; acc[3][1] += av.w * bv.y; acc[3][2] += av.w * bv.z; acc[3][3] += av.w * bv.w;
    }
    __syncthreads();
  }
#pragma unroll
  for (int ii = 0; ii < 4; ii++) {
    int r = row0 + ty * 4 + ii;
    float bsv = bscale ? bscale[r] : 1.f;
#pragma unroll
    for (int jj = 0; jj < 4; jj++) {
      int j = col0 + tx * 4 + jj;
      if (edge && j >= N) continue;
      float v = acc[ii][jj];
      if (bias) v += bsv * bias[j];
      if (relu) v = fmaxf(v, 0.f);
      if (tstore) {
        int bb = r / NPB, n = r % NPB;
        Cc[(size_t)bb * COUT * NPB + (size_t)j * NPB + n] = v;
      } else {
        Cc[(size_t)r * N + j] = v;
      }
    }
  }
}

extern "C" void kernel_launch(void* const* d_in, const int* in_sizes, int n_in,
                              void* d_out, int out_size, void* d_ws, size_t ws_size,
                              hipStream_t stream) {
  const float* x      = (const float*)d_in[0];
  const float* kmap_w = (const float*)d_in[1];
  const float* kmap_b = (const float*)d_in[2];
  const float* kfc_w  = (const float*)d_in[3];
  const float* kfc_b  = (const float*)d_in[4];
  const float* kmu_w  = (const float*)d_in[5];
  const float* kmu_b  = (const float*)d_in[6];
  const float* kdec_w = (const float*)d_in[7];
  const float* kdec_b = (const float*)d_in[8];
  const float* ec1_w  = (const float*)d_in[9];
  const float* ec1_b  = (const float*)d_in[10];
  const float* ec2_w  = (const float*)d_in[11];
  const float* ec2_b  = (const float*)d_in[12];
  const float* fc_w   = (const float*)d_in[13];
  const float* fc_b   = (const float*)d_in[14];
  const float* io_w   = (const float*)d_in[15];
  const float* io_b   = (const float*)d_in[16];
  const float* up_w   = (const float*)d_in[17];
  const float* up_b   = (const float*)d_in[18];

  // ---- workspace layout (liveness-aliased; total ~49.4 MB) ----
  char* ws = (char*)d_ws;
  size_t off = 0;
  auto alloc = [&](size_t bytes) -> void* {
    void* p = ws + off;
    off += (bytes + 255) & ~(size_t)255;
    return p;
  };
  float* xf    = (float*)alloc((size_t)NODES * C * 4);   // later reused as bufH2
  float* sqb   = (float*)alloc((size_t)NODES * 4);
  float* rs    = (float*)alloc((size_t)NODES * 4);
  int*   kint  = (int*)alloc((size_t)NODES * 4);
  int*   nn    = (int*)alloc((size_t)NODES * KNN * 4);
  float* bufH1 = (float*)alloc((size_t)NODES * C * 4);   // NODES*C*4 is 256-aligned
  float* bufS  = (float*)alloc((size_t)NODES * C * 4);   // contiguous after bufH1
  float* bufXio = (float*)alloc((size_t)NODES * COUT * 4);
  float* hK     = bufXio;  // 6272*500 floats < NODES*COUT; dead before xio written
  // knn partials also alias bufXio (dead after knn_merge, before xio GEMM):
  float* pk_d   = bufXio;                                   // NODES*MSPLIT*9 floats
  int*   pk_i   = (int*)(bufXio + (size_t)NODES * MSPLIT * KNN);  // 14.5MB total <= 19.2MB
  float* bufH2  = xf;      // xf dead after xio GEMM
  float* bufAgg = bufH1;   // spans bufH1+bufS (exactly NODES*COUT*4); both dead

  transpose_kernel<<<dim3(98, 3, 8), dim3(32, 8), 0, stream>>>(x, xf);
  sq_kernel<<<98, 256, 0, stream>>>(xf, sqb);

  // VAE head: 96->500 GEMM (M-chunked, uses hK alias) + fused tail -> k_int
  for (int c = 0; c < 4; c++) {
    gemm_kernel<<<dim3(98, 8), 256, 0, stream>>>(
        xf + (size_t)c * 6272 * C, nullptr, 96, 96, nullptr, nullptr,
        kmap_w, 500, 0, kmap_b, nullptr, hK, 6272, 500, 0, 0);
    vae_tail_kernel<<<784, 256, 0, stream>>>(hK, kfc_w, kfc_b, kmu_w, kmu_b,
                                             kdec_w, kdec_b, c * 6272, kint, rs);
  }

  // kNN: m-split partials + merge (partials alias bufXio; hK dead now)
  knn_kernel<<<dim3(49, 8, MSPLIT), 256, 0, stream>>>(xf, sqb, pk_d, pk_i);
  knn_merge_kernel<<<98, 256, 0, stream>>>(pk_d, pk_i, nn);

  // EdgeConv layer 1: h1 = relu(k*xi@(W1-W2) + S@W2 + k*b)
  gather_kernel<<<2352, 256, 0, stream>>>(xf, nn, kint, bufS);
  gemm_kernel<<<dim3(392, 2), 256, 0, stream>>>(
      xf, bufS, 96, 192, rs, nullptr, ec1_w, 96, 1, ec1_b, rs, bufH1, NODES, 96, 1, 0);

  // xio = nodes @ io_w + io_b  (overwrites bufXio; partials dead)
  gemm_kernel<<<dim3(392, 3), 256, 0, stream>>>(
      xf, nullptr, 96, 96, nullptr, nullptr, io_w, COUT, 0, io_b, nullptr, bufXio, NODES, COUT, 0, 0);

  // EdgeConv layer 2 (no relu); output aliases xf (dead after xio GEMM)
  gather_kernel<<<2352, 256, 0, stream>>>(bufH1, nn, kint, bufS);
  gemm_kernel<<<dim3(392, 2), 256, 0, stream>>>(
      bufH1, bufS, 96, 192, rs, nullptr, ec2_w, 96, 1, ec2_b, rs, bufH2, NODES, 96, 0, 0);

  // agg = h2 @ fc_w + fc_b (aliases bufH1+bufS, both dead)
  gemm_kernel<<<dim3(392, 3), 256, 0, stream>>>(
      bufH2, nullptr, 96, 96, nullptr, nullptr, fc_w, COUT, 0, fc_b, nullptr, bufAgg, NODES, COUT, 0, 0);

  // final: relu([xio | agg] @ up_w + up_b), transpose-store to [B, 192, 3136]
  gemm_kernel<<<dim3(392, 3), 256, 0, stream>>>(
      bufXio, bufAgg, 192, 384, nullptr, nullptr, up_w, COUT, 0, up_b, nullptr,
      (float*)d_out, NODES, COUT, 1, 1);
}

// Round 6
// 890.500 us; speedup vs baseline: 1.4144x; 1.4144x over previous
//
#include <hip/hip_runtime.h>

#define NODES 25088
#define NB 8
#define NPB 3136   // nodes per batch (56*56)
#define C 96
#define KNN 9
#define COUT 192
#define MSPLIT 2   // m-range halves for knn filter
#define T12 12     // filter depth per half (>= 10 guarantees exact top-9 coverage)

typedef float f32x4 __attribute__((ext_vector_type(4)));
typedef short s16x8 __attribute__((ext_vector_type(8)));

__device__ __forceinline__ unsigned short f2bf(float x) {
  unsigned u = __float_as_uint(x);
  return (unsigned short)((u + 0x7fffu + ((u >> 16) & 1u)) >> 16);
}
__device__ __forceinline__ float bf2f(unsigned short h) {
  return __uint_as_float(((unsigned)h) << 16);
}

// ---------------- transpose x [B,C,N] -> xf [B*N, C] ----------------
__global__ void transpose_kernel(const float* __restrict__ x, float* __restrict__ xf) {
  __shared__ float t[32][33];
  int b = blockIdx.z, ct = blockIdx.y, nt = blockIdx.x;
  int tx = threadIdx.x, ty = threadIdx.y;
  int n0 = nt * 32, c0 = ct * 32;
  const float* xb = x + (size_t)b * C * NPB;
#pragma unroll
  for (int i = 0; i < 4; i++) {
    int c = c0 + ty + i * 8;
    t[ty + i * 8][tx] = xb[(size_t)c * NPB + n0 + tx];
  }
  __syncthreads();
  float* xfb = xf + (size_t)b * NPB * C;
#pragma unroll
  for (int i = 0; i < 4; i++) {
    int n = n0 + ty + i * 8;
    xfb[(size_t)n * C + c0 + tx] = t[tx][ty + i * 8];
  }
}

// ---------------- per-node squared norm ----------------
__global__ void sq_kernel(const float* __restrict__ xf, float* __restrict__ sq) {
  int node = blockIdx.x * 256 + threadIdx.x;
  const float4* r = (const float4*)(xf + (size_t)node * C);
  float s = 0.f;
#pragma unroll
  for (int i = 0; i < 24; i++) {
    float4 v = r[i];
    s += v.x * v.x + v.y * v.y + v.z * v.z + v.w * v.w;
  }
  sq[node] = s;
}

// ---------------- fp32 -> bf16 hi/lo split ----------------
__global__ void split_kernel(const float* __restrict__ xf,
                             unsigned short* __restrict__ xh,
                             unsigned short* __restrict__ xl) {
  int i = blockIdx.x * 256 + threadIdx.x;  // one float4 per thread
  float4 v = ((const float4*)xf)[i];
  ushort4 h, l;
  h.x = f2bf(v.x); l.x = f2bf(v.x - bf2f(h.x));
  h.y = f2bf(v.y); l.y = f2bf(v.y - bf2f(h.y));
  h.z = f2bf(v.z); l.z = f2bf(v.z - bf2f(h.z));
  h.w = f2bf(v.w); l.w = f2bf(v.w - bf2f(h.w));
  ((ushort4*)xh)[i] = h;
  ((ushort4*)xl)[i] = l;
}

// ---------------- MFMA kNN filter: approx top-12 per m-half per query ----------------
// grid (49, 8, MSPLIT), block 256 (4 waves). Block: 64 queries x half the m-range.
// S[64q x 64m] per tile via split-bf16 mfma (4 products), selection scan from LDS.
// All 12 MFMAs per m-strip live in ONE asm block with leading/trailing s_nop
// hazard guards INSIDE the block, so the compiler cannot schedule VALU/LDS
// reads of the accumulator into the hazard window (R5's divergence cause).
__global__ __launch_bounds__(256) void knn_mfma_kernel(
    const unsigned short* __restrict__ xh, const unsigned short* __restrict__ xl,
    const float* __restrict__ sq, int* __restrict__ pk_i) {
  __shared__ unsigned short mh[64 * 104];
  __shared__ unsigned short mlo[64 * 104];
  __shared__ float S[64 * 65];
  __shared__ float sqs[64];
  int tid = threadIdx.x;
  int lane = tid & 63, wv = tid >> 6;
  int b = blockIdx.y, z = blockIdx.z;
  int q0 = blockIdx.x * 64;
  int bbase = b * NPB;
  int t0 = (z * 49) / MSPLIT, t1 = ((z + 1) * 49) / MSPLIT;

  // A-fragments (this wave's 16 queries), fixed across tiles.
  int qrow = q0 + wv * 16 + (lane & 15);
  int koff = (lane >> 4) * 8;
  s16x8 ah[3], al[3];
  {
    const unsigned short* ph = xh + (size_t)(bbase + qrow) * 96 + koff;
    const unsigned short* pl = xl + (size_t)(bbase + qrow) * 96 + koff;
#pragma unroll
    for (int kc = 0; kc < 3; kc++) {
      ah[kc] = *(const s16x8*)(ph + kc * 32);
      al[kc] = *(const s16x8*)(pl + kc * 32);
    }
  }
  float sqr = sq[bbase + q0 + lane];  // scan role: lane = query

  float fd[T12];
  int fi[T12];
#pragma unroll
  for (int k = 0; k < T12; k++) { fd[k] = 3.4e38f; fi[k] = 0; }

  int srow = tid >> 2, sseg = tid & 3;  // staging: 4 threads per row, 3 segs each

  for (int t = t0; t < t1; t++) {
    int m0 = t * 64;
    __syncthreads();
    {
      const unsigned short* gh = xh + (size_t)(bbase + m0 + srow) * 96;
      const unsigned short* gl = xl + (size_t)(bbase + m0 + srow) * 96;
#pragma unroll
      for (int i = 0; i < 3; i++) {
        int s = sseg * 3 + i;
        *(s16x8*)(mh + srow * 104 + s * 8) = *(const s16x8*)(gh + s * 8);
        *(s16x8*)(mlo + srow * 104 + s * 8) = *(const s16x8*)(gl + s * 8);
      }
      if (tid < 64) sqs[tid] = sq[bbase + m0 + tid];
    }
    __syncthreads();

    int qloc = wv * 16 + (lane >> 4) * 4;
    int mcol = lane & 15;
#pragma unroll
    for (int ms = 0; ms < 4; ms++) {
      int boff = (ms * 16 + (lane & 15)) * 104 + koff;
      s16x8 bh0 = *(const s16x8*)(mh + boff);
      s16x8 bl0 = *(const s16x8*)(mlo + boff);
      s16x8 bh1 = *(const s16x8*)(mh + boff + 32);
      s16x8 bl1 = *(const s16x8*)(mlo + boff + 32);
      s16x8 bh2 = *(const s16x8*)(mh + boff + 64);
      s16x8 bl2 = *(const s16x8*)(mlo + boff + 64);
      f32x4 acc = (f32x4){0.f, 0.f, 0.f, 0.f};
      asm volatile(
          "s_nop 1\n\t"
          "v_mfma_f32_16x16x32_bf16 %0, %1, %7, %0\n\t"
          "v_mfma_f32_16x16x32_bf16 %0, %1, %8, %0\n\t"
          "v_mfma_f32_16x16x32_bf16 %0, %2, %7, %0\n\t"
          "v_mfma_f32_16x16x32_bf16 %0, %2, %8, %0\n\t"
          "v_mfma_f32_16x16x32_bf16 %0, %3, %9, %0\n\t"
          "v_mfma_f32_16x16x32_bf16 %0, %3, %10, %0\n\t"
          "v_mfma_f32_16x16x32_bf16 %0, %4, %9, %0\n\t"
          "v_mfma_f32_16x16x32_bf16 %0, %4, %10, %0\n\t"
          "v_mfma_f32_16x16x32_bf16 %0, %5, %11, %0\n\t"
          "v_mfma_f32_16x16x32_bf16 %0, %5, %12, %0\n\t"
          "v_mfma_f32_16x16x32_bf16 %0, %6, %11, %0\n\t"
          "v_mfma_f32_16x16x32_bf16 %0, %6, %12, %0\n\t"
          "s_nop 7\n\t"
          "s_nop 7\n\t"
          "s_nop 7"
          : "+v"(acc)
          : "v"(ah[0]), "v"(al[0]), "v"(ah[1]), "v"(al[1]), "v"(ah[2]),
            "v"(al[2]), "v"(bh0), "v"(bl0), "v"(bh1), "v"(bl1), "v"(bh2),
            "v"(bl2));
      // C/D layout: row(q) = quad*4+reg, col(m) = lane&15  [verified mapping]
#pragma unroll
      for (int r = 0; r < 4; r++) {
        S[(qloc + r) * 65 + ms * 16 + mcol] = acc[r];
      }
    }
    __syncthreads();

    // scan: lane = query, wave wv scans m-strip [wv*16, wv*16+16)
#pragma unroll
    for (int i = 0; i < 16; i++) {
      int mloc = wv * 16 + i;
      float d = fmaf(-2.f, S[lane * 65 + mloc], sqr + sqs[mloc]);
      int m = m0 + mloc;
      if (d < fd[T12 - 1]) {
        fd[T12 - 1] = d;
        fi[T12 - 1] = m;
#pragma unroll
        for (int k = T12 - 1; k > 0; --k) {
          if (fd[k] < fd[k - 1]) {
            float td = fd[k]; fd[k] = fd[k - 1]; fd[k - 1] = td;
            int ti = fi[k]; fi[k] = fi[k - 1]; fi[k - 1] = ti;
          }
        }
      }
    }
  }

  // merge the 4 wave-strips (per query) via LDS; aliases dead mh/mlo
  __syncthreads();
  float* cd = (float*)mh;  // 4*64*12 floats = 12288 B <= 13312
  int* ci = (int*)mlo;
#pragma unroll
  for (int k = 0; k < T12; k++) {
    cd[(wv * 64 + lane) * T12 + k] = fd[k];
    ci[(wv * 64 + lane) * T12 + k] = fi[k];
  }
  __syncthreads();
  if (wv == 0) {
    float gd[T12];
    int gi[T12];
#pragma unroll
    for (int k = 0; k < T12; k++) { gd[k] = 3.4e38f; gi[k] = 0; }
    for (int s = 0; s < 4; s++) {
#pragma unroll
      for (int k = 0; k < T12; k++) {
        float d = cd[(s * 64 + lane) * T12 + k];
        int m = ci[(s * 64 + lane) * T12 + k];
        if (d < gd[T12 - 1]) {
          gd[T12 - 1] = d;
          gi[T12 - 1] = m;
#pragma unroll
          for (int kk = T12 - 1; kk > 0; --kk) {
            if (gd[kk] < gd[kk - 1]) {
              float td = gd[kk]; gd[kk] = gd[kk - 1]; gd[kk - 1] = td;
              int ti = gi[kk]; gi[kk] = gi[kk - 1]; gi[kk - 1] = ti;
            }
          }
        }
      }
    }
    size_t base = ((size_t)(bbase + q0 + lane) * MSPLIT + z) * T12;
#pragma unroll
    for (int k = 0; k < T12; k++) pk_i[base + k] = bbase + gi[k];
  }
}

// ---------------- exact fp32 rescore of 24 candidates -> top-9 ----------------
__global__ void rescore_kernel(const float* __restrict__ xf, const float* __restrict__ sq,
                               const int* __restrict__ pk_i, int* __restrict__ nn) {
  int q = blockIdx.x * 256 + threadIdx.x;
  float4 qr[24];
  const float4* qp = (const float4*)(xf + (size_t)q * C);
#pragma unroll
  for (int i = 0; i < 24; i++) qr[i] = qp[i];
  float sqq = sq[q];
  float fd[KNN];
  int fi[KNN];
#pragma unroll
  for (int k = 0; k < KNN; k++) { fd[k] = 3.4e38f; fi[k] = 0x7fffffff; }
  const int* cp = pk_i + (size_t)q * (MSPLIT * T12);
  for (int c = 0; c < MSPLIT * T12; c++) {
    int j = cp[c];
    const float4* mp = (const float4*)(xf + (size_t)j * C);
    float d0 = 0.f, d1 = 0.f, d2 = 0.f, d3 = 0.f;
#pragma unroll
    for (int i = 0; i < 24; i++) {
      float4 mv = mp[i];
      d0 += qr[i].x * mv.x;
      d1 += qr[i].y * mv.y;
      d2 += qr[i].z * mv.z;
      d3 += qr[i].w * mv.w;
    }
    float d = (sqq - 2.0f * ((d0 + d1) + (d2 + d3))) + sq[j];
    if (d < fd[KNN - 1] || (d == fd[KNN - 1] && j < fi[KNN - 1])) {
      fd[KNN - 1] = d;
      fi[KNN - 1] = j;
#pragma unroll
      for (int k = KNN - 1; k > 0; --k) {
        bool sw = (fd[k] < fd[k - 1]) || (fd[k] == fd[k - 1] && fi[k] < fi[k - 1]);
        if (sw) {
          float td = fd[k]; fd[k] = fd[k - 1]; fd[k - 1] = td;
          int ti = fi[k]; fi[k] = fi[k - 1]; fi[k - 1] = ti;
        }
      }
    }
  }
#pragma unroll
  for (int k = 0; k < KNN; k++) nn[(size_t)q * KNN + k] = fi[k];
}

// ---------------- fused VAE tail: hK[500] -> 64 -> 32 -> 9 -> argmax ----------------
__global__ void vae_tail_kernel(const float* __restrict__ hK,
                                const float* __restrict__ kfc_w, const float* __restrict__ kfc_b,
                                const float* __restrict__ kmu_w, const float* __restrict__ kmu_b,
                                const float* __restrict__ kdec_w, const float* __restrict__ kdec_b,
                                int node_base, int* __restrict__ kint, float* __restrict__ rs) {
  __shared__ float hrow[8][500];
  __shared__ float h64s[8][64];
  __shared__ float mus[8][32];
  __shared__ float lg[8][9];
  int tid = threadIdx.x;
  int nb = blockIdx.x * 8;
  for (int f = tid; f < 8 * 500; f += 256) {
    int nl = f / 500, q = f % 500;
    hrow[nl][q] = hK[(size_t)(nb + nl) * 500 + q];
  }
  __syncthreads();
  {
    int nl0 = tid >> 6, j = tid & 63;
    float a0 = 0.f, a1 = 0.f;
    for (int q = 0; q < 500; q++) {
      float w = kfc_w[q * 64 + j];
      a0 += hrow[nl0][q] * w;
      a1 += hrow[nl0 + 4][q] * w;
    }
    float bj = kfc_b[j];
    h64s[nl0][j] = fmaxf(a0 + bj, 0.f);
    h64s[nl0 + 4][j] = fmaxf(a1 + bj, 0.f);
  }
  __syncthreads();
  {
    int nl = tid / 32, j = tid % 32;
    float a = 0.f;
#pragma unroll
    for (int q = 0; q < 64; q++) a += h64s[nl][q] * kmu_w[q * 32 + j];
    mus[nl][j] = a + kmu_b[j];
  }
  __syncthreads();
  if (tid < 72) {
    int nl = tid / 9, j = tid % 9;
    float a = 0.f;
#pragma unroll
    for (int q = 0; q < 32; q++) a += mus[nl][q] * kdec_w[q * 9 + j];
    lg[nl][j] = a + kdec_b[j];
  }
  __syncthreads();
  if (tid < 8) {
    float best = lg[tid][0];
    int bi = 0;
#pragma unroll
    for (int j = 1; j < 9; j++) {
      if (lg[tid][j] > best) { best = lg[tid][j]; bi = j; }
    }
    kint[node_base + nb + tid] = bi;
    rs[node_base + nb + tid] = (float)bi;
  }
}

// ---------------- gather-sum of kept neighbors ----------------
__global__ void gather_kernel(const float* __restrict__ feat, const int* __restrict__ nn,
                              const int* __restrict__ kint, float* __restrict__ out) {
  int idx = blockIdx.x * 256 + threadIdx.x;
  int node = idx / 24, c4 = idx % 24;
  int kc = kint[node];
  const int* nr = nn + (size_t)node * KNN;
  float4 acc = make_float4(0.f, 0.f, 0.f, 0.f);
  for (int k = 0; k < kc; k++) {
    int j = nr[k];
    float4 v = ((const float4*)(feat + (size_t)j * C))[c4];
    acc.x += v.x; acc.y += v.y; acc.z += v.z; acc.w += v.w;
  }
  ((float4*)(out + (size_t)node * C))[c4] = acc;
}

// ---------------- generic fp32 GEMM ----------------
// C[M,N] = [A0 (rowscale sc0) | A1 (rowscale sc1)] @ B' + bscale*bias, opt relu,
// opt transpose-store to [B, COUT, NPB]. bmode 1: B' rows k<96 are B[k]-B[k+96].
__global__ __launch_bounds__(256) void gemm_kernel(
    const float* __restrict__ A0, const float* __restrict__ A1, int K0, int Ktot,
    const float* __restrict__ sc0, const float* __restrict__ sc1,
    const float* __restrict__ B, int ldb, int bmode,
    const float* __restrict__ bias, const float* __restrict__ bscale,
    float* __restrict__ Cc, int M, int N, int relu, int tstore) {
  __shared__ float As[16][68];
  __shared__ float Bs[16][68];
  int tid = threadIdx.x;
  int tx = tid & 15, ty = tid >> 4;
  int row0 = blockIdx.x * 64, col0 = blockIdx.y * 64;
  float acc[4][4] = {};
  int ai = tid >> 2;          // 0..63
  int ak = (tid & 3) * 4;     // 0,4,8,12
  int bk = tid >> 4;          // 0..15
  int bj = (tid & 15) * 4;    // 0..60
  bool edge = (col0 + 64 > N);

  for (int k0 = 0; k0 < Ktot; k0 += 16) {
    {
      const float* Ap;
      const float* sc;
      int lda, kk;
      if (k0 < K0) { Ap = A0; lda = K0; sc = sc0; kk = k0; }
      else { Ap = A1; lda = Ktot - K0; sc = sc1; kk = k0 - K0; }
      int r = row0 + ai;
      float4 v = *(const float4*)(Ap + (size_t)r * lda + kk + ak);
      if (sc) { float s = sc[r]; v.x *= s; v.y *= s; v.z *= s; v.w *= s; }
      As[ak + 0][ai] = v.x;
      As[ak + 1][ai] = v.y;
      As[ak + 2][ai] = v.z;
      As[ak + 3][ai] = v.w;
    }
    {
      int kg = k0 + bk;
      int j = col0 + bj;
      float4 v;
      if (!edge) {
        v = *(const float4*)(B + (size_t)kg * ldb + j);
        if (bmode == 1 && kg < 96) {
          float4 w = *(const float4*)(B + (size_t)(kg + 96) * ldb + j);
          v.x -= w.x; v.y -= w.y; v.z -= w.z; v.w -= w.w;
        }
      } else {
        float tmp[4];
#pragma unroll
        for (int e = 0; e < 4; e++) {
          int jj = j + e;
          float val = 0.f;
          if (jj < N) {
            val = B[(size_t)kg * ldb + jj];
            if (bmode == 1 && kg < 96) val -= B[(size_t)(kg + 96) * ldb + jj];
          }
          tmp[e] = val;
        }
        v = make_float4(tmp[0], tmp[1], tmp[2], tmp[3]);
      }
      *(float4*)&Bs[bk][bj] = v;
    }
    __syncthreads();
#pragma unroll
    for (int kk = 0; kk < 16; kk++) {
      float4 av = *(const float4*)&As[kk][ty * 4];
      float4 bv = *(const float4*)&Bs[kk][tx * 4];
      acc[0][0] += av.x * bv.x; acc[0][1] += av.x * bv.y; acc[0][2] += av.x * bv.z; acc[0][3] += av.x * bv.w;
      acc[1][0] += av.y * bv.x; acc[1][1] += av.y * bv.y; acc[1][2] += av.y * bv.z; acc[1][3] += av.y * bv.w;
      acc[2][0] += av.z * bv.x; acc[2][1] += av.z * bv.y; acc[2][2] += av.z * bv.z; acc[2][3] += av.z * bv.w;
      acc[3][0] += av.w * bv.x; acc[3][1] += av.w * bv.y; acc[3][2] += av.w * bv.z; acc[3][3] += av.w * bv.w;
    }
    __syncthreads();
  }
#pragma unroll
  for (int ii = 0; ii < 4; ii++) {
    int r = row0 + ty * 4 + ii;
    float bsv = bscale ? bscale[r] : 1.f;
#pragma unroll
    for (int jj = 0; jj < 4; jj++) {
      int j = col0 + tx * 4 + jj;
      if (edge && j >= N) continue;
      float v = acc[ii][jj];
      if (bias) v += bsv * bias[j];
      if (relu) v = fmaxf(v, 0.f);
      if (tstore) {
        int bb = r / NPB, n = r % NPB;
        Cc[(size_t)bb * COUT * NPB + (size_t)j * NPB + n] = v;
      } else {
        Cc[(size_t)r * N + j] = v;
      }
    }
  }
}

extern "C" void kernel_launch(void* const* d_in, const int* in_sizes, int n_in,
                              void* d_out, int out_size, void* d_ws, size_t ws_size,
                              hipStream_t stream) {
  const float* x      = (const float*)d_in[0];
  const float* kmap_w = (const float*)d_in[1];
  const float* kmap_b = (const float*)d_in[2];
  const float* kfc_w  = (const float*)d_in[3];
  const float* kfc_b  = (const float*)d_in[4];
  const float* kmu_w  = (const float*)d_in[5];
  const float* kmu_b  = (const float*)d_in[6];
  const float* kdec_w = (const float*)d_in[7];
  const float* kdec_b = (const float*)d_in[8];
  const float* ec1_w  = (const float*)d_in[9];
  const float* ec1_b  = (const float*)d_in[10];
  const float* ec2_w  = (const float*)d_in[11];
  const float* ec2_b  = (const float*)d_in[12];
  const float* fc_w   = (const float*)d_in[13];
  const float* fc_b   = (const float*)d_in[14];
  const float* io_w   = (const float*)d_in[15];
  const float* io_b   = (const float*)d_in[16];
  const float* up_w   = (const float*)d_in[17];
  const float* up_b   = (const float*)d_in[18];

  // ---- workspace layout (liveness-aliased; total ~49.4 MB) ----
  char* ws = (char*)d_ws;
  size_t off = 0;
  auto alloc = [&](size_t bytes) -> void* {
    void* p = ws + off;
    off += (bytes + 255) & ~(size_t)255;
    return p;
  };
  float* xf    = (float*)alloc((size_t)NODES * C * 4);   // later reused as bufH2
  float* sqb   = (float*)alloc((size_t)NODES * 4);
  float* rs    = (float*)alloc((size_t)NODES * 4);
  int*   kint  = (int*)alloc((size_t)NODES * 4);
  int*   nn    = (int*)alloc((size_t)NODES * KNN * 4);
  float* bufH1 = (float*)alloc((size_t)NODES * C * 4);   // NODES*C*4 is 256-aligned
  float* bufS  = (float*)alloc((size_t)NODES * C * 4);   // contiguous after bufH1
  float* bufXio = (float*)alloc((size_t)NODES * COUT * 4);
  float* hK     = bufXio;  // VAE intermediate; dead before knn filter writes pk_i
  int*   pk_i   = (int*)bufXio;  // NODES*24 ints = 2.4 MB; dead before xio GEMM
  unsigned short* xh = (unsigned short*)bufH1;  // bf16 hi; dead before h1 GEMM writes
  unsigned short* xl = (unsigned short*)bufS;   // bf16 lo; dead before gather1 writes
  float* bufH2  = xf;      // xf dead after xio GEMM
  float* bufAgg = bufH1;   // spans bufH1+bufS (exactly NODES*COUT*4); both dead

  transpose_kernel<<<dim3(98, 3, 8), dim3(32, 8), 0, stream>>>(x, xf);
  sq_kernel<<<98, 256, 0, stream>>>(xf, sqb);
  split_kernel<<<2352, 256, 0, stream>>>(xf, xh, xl);

  // VAE head: 96->500 GEMM (M-chunked, uses hK alias) + fused tail -> k_int
  for (int c = 0; c < 4; c++) {
    gemm_kernel<<<dim3(98, 8), 256, 0, stream>>>(
        xf + (size_t)c * 6272 * C, nullptr, 96, 96, nullptr, nullptr,
        kmap_w, 500, 0, kmap_b, nullptr, hK, 6272, 500, 0, 0);
    vae_tail_kernel<<<784, 256, 0, stream>>>(hK, kfc_w, kfc_b, kmu_w, kmu_b,
                                             kdec_w, kdec_b, c * 6272, kint, rs);
  }

  // kNN: MFMA split-bf16 filter (top-12 per half) + exact fp32 rescore -> top-9
  knn_mfma_kernel<<<dim3(49, 8, MSPLIT), 256, 0, stream>>>(xh, xl, sqb, pk_i);
  rescore_kernel<<<98, 256, 0, stream>>>(xf, sqb, pk_i, nn);

  // EdgeConv layer 1: h1 = relu(k*xi@(W1-W2) + S@W2 + k*b)
  gather_kernel<<<2352, 256, 0, stream>>>(xf, nn, kint, bufS);
  gemm_kernel<<<dim3(392, 2), 256, 0, stream>>>(
      xf, bufS, 96, 192, rs, nullptr, ec1_w, 96, 1, ec1_b, rs, bufH1, NODES, 96, 1, 0);

  // xio = nodes @ io_w + io_b  (overwrites bufXio; pk_i dead)
  gemm_kernel<<<dim3(392, 3), 256, 0, stream>>>(
      xf, nullptr, 96, 96, nullptr, nullptr, io_w, COUT, 0, io_b, nullptr, bufXio, NODES, COUT, 0, 0);

  // EdgeConv layer 2 (no relu); output aliases xf (dead after xio GEMM)
  gather_kernel<<<2352, 256, 0, stream>>>(bufH1, nn, kint, bufS);
  gemm_kernel<<<dim3(392, 2), 256, 0, stream>>>(
      bufH1, bufS, 96, 192, rs, nullptr, ec2_w, 96, 1, ec2_b, rs, bufH2, NODES, 96, 0, 0);

  // agg = h2 @ fc_w + fc_b (aliases bufH1+bufS, both dead)
  gemm_kernel<<<dim3(392, 3), 256, 0, stream>>>(
      bufH2, nullptr, 96, 96, nullptr, nullptr, fc_w, COUT, 0, fc_b, nullptr, bufAgg, NODES, COUT, 0, 0);

  // final: relu([xio | agg] @ up_w + up_b), transpose-store to [B, 192, 3136]
  gemm_kernel<<<dim3(392, 3), 256, 0, stream>>>(
      bufXio, bufAgg, 192, 384, nullptr, nullptr, up_w, COUT, 0, up_b, nullptr,
      (float*)d_out, NODES, COUT, 1, 1);
}

// Round 7
// 881.451 us; speedup vs baseline: 1.4289x; 1.0103x over previous
//
#include <hip/hip_runtime.h>

#define NODES 25088
#define NB 8
#define NPB 3136   // nodes per batch (56*56)
#define C 96
#define KNN 9
#define COUT 192
#define MSPLIT 2   // m-range halves for knn filter
#define T12 12     // filter depth per half (>= 10 guarantees exact top-9 coverage)

typedef float f32x4 __attribute__((ext_vector_type(4)));
typedef float f32x16 __attribute__((ext_vector_type(16)));
typedef short s16x8 __attribute__((ext_vector_type(8)));

__device__ __forceinline__ unsigned short f2bf(float x) {
  unsigned u = __float_as_uint(x);
  return (unsigned short)((u + 0x7fffu + ((u >> 16) & 1u)) >> 16);
}
__device__ __forceinline__ float bf2f(unsigned short h) {
  return __uint_as_float(((unsigned)h) << 16);
}

// ---------------- transpose x [B,C,N] -> xf [B*N, C] ----------------
__global__ void transpose_kernel(const float* __restrict__ x, float* __restrict__ xf) {
  __shared__ float t[32][33];
  int b = blockIdx.z, ct = blockIdx.y, nt = blockIdx.x;
  int tx = threadIdx.x, ty = threadIdx.y;
  int n0 = nt * 32, c0 = ct * 32;
  const float* xb = x + (size_t)b * C * NPB;
#pragma unroll
  for (int i = 0; i < 4; i++) {
    int c = c0 + ty + i * 8;
    t[ty + i * 8][tx] = xb[(size_t)c * NPB + n0 + tx];
  }
  __syncthreads();
  float* xfb = xf + (size_t)b * NPB * C;
#pragma unroll
  for (int i = 0; i < 4; i++) {
    int n = n0 + ty + i * 8;
    xfb[(size_t)n * C + c0 + tx] = t[tx][ty + i * 8];
  }
}

// ---------------- per-node squared norm ----------------
__global__ void sq_kernel(const float* __restrict__ xf, float* __restrict__ sq) {
  int node = blockIdx.x * 256 + threadIdx.x;
  const float4* r = (const float4*)(xf + (size_t)node * C);
  float s = 0.f;
#pragma unroll
  for (int i = 0; i < 24; i++) {
    float4 v = r[i];
    s += v.x * v.x + v.y * v.y + v.z * v.z + v.w * v.w;
  }
  sq[node] = s;
}

// ---------------- fp32 -> bf16 hi/lo split ----------------
__global__ void split_kernel(const float* __restrict__ xf,
                             unsigned short* __restrict__ xh,
                             unsigned short* __restrict__ xl) {
  int i = blockIdx.x * 256 + threadIdx.x;  // one float4 per thread
  float4 v = ((const float4*)xf)[i];
  ushort4 h, l;
  h.x = f2bf(v.x); l.x = f2bf(v.x - bf2f(h.x));
  h.y = f2bf(v.y); l.y = f2bf(v.y - bf2f(h.y));
  h.z = f2bf(v.z); l.z = f2bf(v.z - bf2f(h.z));
  h.w = f2bf(v.w); l.w = f2bf(v.w - bf2f(h.w));
  ((ushort4*)xh)[i] = h;
  ((ushort4*)xl)[i] = l;
}

// ---------------- MFMA kNN filter: approx top-12 per m-half per query ----------------
// grid (49, 8, MSPLIT), block 256 (4 waves). Block: 64 queries x half the m-range.
// 32x32x16 bf16 MFMA; wave wv owns S quadrant (rows (wv>>1)*32.., cols (wv&1)*32..).
// A-fragments (queries, hi+lo) live in registers for the whole kernel; per tile
// each wave reads only 12 B-fragments (b128) from LDS and issues 18 MFMAs in a
// single asm block with s_nop hazard guards inside (R6-proven pattern).
// Split products: ah*bh + al*bh + ah*bl (lo*lo dropped, error ~2^-18).
__global__ __launch_bounds__(256) void knn_mfma_kernel(
    const unsigned short* __restrict__ xh, const unsigned short* __restrict__ xl,
    const float* __restrict__ sq, int* __restrict__ pk_i) {
  __shared__ unsigned short mh[64 * 104];
  __shared__ unsigned short mlo[64 * 104];
  __shared__ float S[64 * 65];
  __shared__ float sqs[64];
  int tid = threadIdx.x;
  int lane = tid & 63, wv = tid >> 6;
  int b = blockIdx.y, z = blockIdx.z;
  int q0 = blockIdx.x * 64;
  int bbase = b * NPB;
  int t0 = (z * 49) / MSPLIT, t1 = ((z + 1) * 49) / MSPLIT;

  // A-fragments: wave's 32 queries (rows (wv>>1)*32..+31), fixed across tiles.
  // Layout (extrapolated from verified 16x16 rule): A[m=lane&31][k=(lane>>5)*8+j]
  int koff = (lane >> 5) * 8;
  int rowA = bbase + q0 + (wv >> 1) * 32 + (lane & 31);
  s16x8 ah[6], al[6];
  {
    const unsigned short* ph = xh + (size_t)rowA * 96 + koff;
    const unsigned short* pl = xl + (size_t)rowA * 96 + koff;
#pragma unroll
    for (int kc = 0; kc < 6; kc++) {
      ah[kc] = *(const s16x8*)(ph + kc * 16);
      al[kc] = *(const s16x8*)(pl + kc * 16);
    }
  }
  float sqr = sq[bbase + q0 + lane];  // scan role: lane = query

  float fd[T12];
  int fi[T12];
#pragma unroll
  for (int k = 0; k < T12; k++) { fd[k] = 3.4e38f; fi[k] = 0; }

  int srow = tid >> 2, sseg = tid & 3;  // staging: 4 threads per row, 3 segs each

  for (int t = t0; t < t1; t++) {
    int m0 = t * 64;
    __syncthreads();
    {
      const unsigned short* gh = xh + (size_t)(bbase + m0 + srow) * 96;
      const unsigned short* gl = xl + (size_t)(bbase + m0 + srow) * 96;
#pragma unroll
      for (int i = 0; i < 3; i++) {
        int s = sseg * 3 + i;
        *(s16x8*)(mh + srow * 104 + s * 8) = *(const s16x8*)(gh + s * 8);
        *(s16x8*)(mlo + srow * 104 + s * 8) = *(const s16x8*)(gl + s * 8);
      }
      if (tid < 64) sqs[tid] = sq[bbase + m0 + tid];
    }
    __syncthreads();

    // B-fragments for this wave's m-quadrant: B[k=(lane>>5)*8+j][n=lane&31]
    int mrow = (wv & 1) * 32 + (lane & 31);
    s16x8 bh[6], bl[6];
#pragma unroll
    for (int kc = 0; kc < 6; kc++) {
      bh[kc] = *(const s16x8*)(mh + mrow * 104 + kc * 16 + koff);
      bl[kc] = *(const s16x8*)(mlo + mrow * 104 + kc * 16 + koff);
    }

    f32x16 acc = (f32x16){0.f, 0.f, 0.f, 0.f, 0.f, 0.f, 0.f, 0.f,
                          0.f, 0.f, 0.f, 0.f, 0.f, 0.f, 0.f, 0.f};
    asm volatile(
        "s_nop 1\n\t"
        "v_mfma_f32_32x32x16_bf16 %0, %1, %13, %0\n\t"
        "v_mfma_f32_32x32x16_bf16 %0, %7, %13, %0\n\t"
        "v_mfma_f32_32x32x16_bf16 %0, %1, %19, %0\n\t"
        "v_mfma_f32_32x32x16_bf16 %0, %2, %14, %0\n\t"
        "v_mfma_f32_32x32x16_bf16 %0, %8, %14, %0\n\t"
        "v_mfma_f32_32x32x16_bf16 %0, %2, %20, %0\n\t"
        "v_mfma_f32_32x32x16_bf16 %0, %3, %15, %0\n\t"
        "v_mfma_f32_32x32x16_bf16 %0, %9, %15, %0\n\t"
        "v_mfma_f32_32x32x16_bf16 %0, %3, %21, %0\n\t"
        "v_mfma_f32_32x32x16_bf16 %0, %4, %16, %0\n\t"
        "v_mfma_f32_32x32x16_bf16 %0, %10, %16, %0\n\t"
        "v_mfma_f32_32x32x16_bf16 %0, %4, %22, %0\n\t"
        "v_mfma_f32_32x32x16_bf16 %0, %5, %17, %0\n\t"
        "v_mfma_f32_32x32x16_bf16 %0, %11, %17, %0\n\t"
        "v_mfma_f32_32x32x16_bf16 %0, %5, %23, %0\n\t"
        "v_mfma_f32_32x32x16_bf16 %0, %6, %18, %0\n\t"
        "v_mfma_f32_32x32x16_bf16 %0, %12, %18, %0\n\t"
        "v_mfma_f32_32x32x16_bf16 %0, %6, %24, %0\n\t"
        "s_nop 7\n\t"
        "s_nop 7\n\t"
        "s_nop 7"
        : "+v"(acc)
        : "v"(ah[0]), "v"(ah[1]), "v"(ah[2]), "v"(ah[3]), "v"(ah[4]), "v"(ah[5]),
          "v"(al[0]), "v"(al[1]), "v"(al[2]), "v"(al[3]), "v"(al[4]), "v"(al[5]),
          "v"(bh[0]), "v"(bh[1]), "v"(bh[2]), "v"(bh[3]), "v"(bh[4]), "v"(bh[5]),
          "v"(bl[0]), "v"(bl[1]), "v"(bl[2]), "v"(bl[3]), "v"(bl[4]), "v"(bl[5]));

    // C/D layout 32x32: col = lane&31, row = (reg&3) + 8*(reg>>2) + 4*(lane>>5)
    {
      int colbase = (wv & 1) * 32 + (lane & 31);
      int rowbase = (wv >> 1) * 32 + 4 * (lane >> 5);
#pragma unroll
      for (int reg = 0; reg < 16; reg++) {
        int row = rowbase + (reg & 3) + 8 * (reg >> 2);
        S[row * 65 + colbase] = acc[reg];
      }
    }
    __syncthreads();

    // scan: lane = query, wave wv scans m-strip [wv*16, wv*16+16)
#pragma unroll
    for (int i = 0; i < 16; i++) {
      int mloc = wv * 16 + i;
      float d = fmaf(-2.f, S[lane * 65 + mloc], sqr + sqs[mloc]);
      int m = m0 + mloc;
      if (d < fd[T12 - 1]) {
        fd[T12 - 1] = d;
        fi[T12 - 1] = m;
#pragma unroll
        for (int k = T12 - 1; k > 0; --k) {
          if (fd[k] < fd[k - 1]) {
            float td = fd[k]; fd[k] = fd[k - 1]; fd[k - 1] = td;
            int ti = fi[k]; fi[k] = fi[k - 1]; fi[k - 1] = ti;
          }
        }
      }
    }
  }

  // merge the 4 wave-strips (per query) via LDS; aliases dead mh/mlo
  __syncthreads();
  float* cd = (float*)mh;  // 4*64*12 floats = 12288 B <= 13312
  int* ci = (int*)mlo;
#pragma unroll
  for (int k = 0; k < T12; k++) {
    cd[(wv * 64 + lane) * T12 + k] = fd[k];
    ci[(wv * 64 + lane) * T12 + k] = fi[k];
  }
  __syncthreads();
  if (wv == 0) {
    float gd[T12];
    int gi[T12];
#pragma unroll
    for (int k = 0; k < T12; k++) { gd[k] = 3.4e38f; gi[k] = 0; }
    for (int s = 0; s < 4; s++) {
#pragma unroll
      for (int k = 0; k < T12; k++) {
        float d = cd[(s * 64 + lane) * T12 + k];
        int m = ci[(s * 64 + lane) * T12 + k];
        if (d < gd[T12 - 1]) {
          gd[T12 - 1] = d;
          gi[T12 - 1] = m;
#pragma unroll
          for (int kk = T12 - 1; kk > 0; --kk) {
            if (gd[kk] < gd[kk - 1]) {
              float td = gd[kk]; gd[kk] = gd[kk - 1]; gd[kk - 1] = td;
              int ti = gi[kk]; gi[kk] = gi[kk - 1]; gi[kk - 1] = ti;
            }
          }
        }
      }
    }
    size_t base = ((size_t)(bbase + q0 + lane) * MSPLIT + z) * T12;
#pragma unroll
    for (int k = 0; k < T12; k++) pk_i[base + k] = bbase + gi[k];
  }
}

// ---------------- exact fp32 rescore of 24 candidates -> top-9 ----------------
__global__ void rescore_kernel(const float* __restrict__ xf, const float* __restrict__ sq,
                               const int* __restrict__ pk_i, int* __restrict__ nn) {
  int q = blockIdx.x * 256 + threadIdx.x;
  float4 qr[24];
  const float4* qp = (const float4*)(xf + (size_t)q * C);
#pragma unroll
  for (int i = 0; i < 24; i++) qr[i] = qp[i];
  float sqq = sq[q];
  float fd[KNN];
  int fi[KNN];
#pragma unroll
  for (int k = 0; k < KNN; k++) { fd[k] = 3.4e38f; fi[k] = 0x7fffffff; }
  const int* cp = pk_i + (size_t)q * (MSPLIT * T12);
  for (int c = 0; c < MSPLIT * T12; c++) {
    int j = cp[c];
    const float4* mp = (const float4*)(xf + (size_t)j * C);
    float d0 = 0.f, d1 = 0.f, d2 = 0.f, d3 = 0.f;
#pragma unroll
    for (int i = 0; i < 24; i++) {
      float4 mv = mp[i];
      d0 += qr[i].x * mv.x;
      d1 += qr[i].y * mv.y;
      d2 += qr[i].z * mv.z;
      d3 += qr[i].w * mv.w;
    }
    float d = (sqq - 2.0f * ((d0 + d1) + (d2 + d3))) + sq[j];
    if (d < fd[KNN - 1] || (d == fd[KNN - 1] && j < fi[KNN - 1])) {
      fd[KNN - 1] = d;
      fi[KNN - 1] = j;
#pragma unroll
      for (int k = KNN - 1; k > 0; --k) {
        bool sw = (fd[k] < fd[k - 1]) || (fd[k] == fd[k - 1] && fi[k] < fi[k - 1]);
        if (sw) {
          float td = fd[k]; fd[k] = fd[k - 1]; fd[k - 1] = td;
          int ti = fi[k]; fi[k] = fi[k - 1]; fi[k - 1] = ti;
        }
      }
    }
  }
#pragma unroll
  for (int k = 0; k < KNN; k++) nn[(size_t)q * KNN + k] = fi[k];
}

// ---------------- fused VAE tail: hK[500] -> 64 -> 32 -> 9 -> argmax ----------------
__global__ void vae_tail_kernel(const float* __restrict__ hK,
                                const float* __restrict__ kfc_w, const float* __restrict__ kfc_b,
                                const float* __restrict__ kmu_w, const float* __restrict__ kmu_b,
                                const float* __restrict__ kdec_w, const float* __restrict__ kdec_b,
                                int node_base, int* __restrict__ kint, float* __restrict__ rs) {
  __shared__ float hrow[8][500];
  __shared__ float h64s[8][64];
  __shared__ float mus[8][32];
  __shared__ float lg[8][9];
  int tid = threadIdx.x;
  int nb = blockIdx.x * 8;
  for (int f = tid; f < 8 * 500; f += 256) {
    int nl = f / 500, q = f % 500;
    hrow[nl][q] = hK[(size_t)(nb + nl) * 500 + q];
  }
  __syncthreads();
  {
    int nl0 = tid >> 6, j = tid & 63;
    float a0 = 0.f, a1 = 0.f;
    for (int q = 0; q < 500; q++) {
      float w = kfc_w[q * 64 + j];
      a0 += hrow[nl0][q] * w;
      a1 += hrow[nl0 + 4][q] * w;
    }
    float bj = kfc_b[j];
    h64s[nl0][j] = fmaxf(a0 + bj, 0.f);
    h64s[nl0 + 4][j] = fmaxf(a1 + bj, 0.f);
  }
  __syncthreads();
  {
    int nl = tid / 32, j = tid % 32;
    float a = 0.f;
#pragma unroll
    for (int q = 0; q < 64; q++) a += h64s[nl][q] * kmu_w[q * 32 + j];
    mus[nl][j] = a + kmu_b[j];
  }
  __syncthreads();
  if (tid < 72) {
    int nl = tid / 9, j = tid % 9;
    float a = 0.f;
#pragma unroll
    for (int q = 0; q < 32; q++) a += mus[nl][q] * kdec_w[q * 9 + j];
    lg[nl][j] = a + kdec_b[j];
  }
  __syncthreads();
  if (tid < 8) {
    float best = lg[tid][0];
    int bi = 0;
#pragma unroll
    for (int j = 1; j < 9; j++) {
      if (lg[tid][j] > best) { best = lg[tid][j]; bi = j; }
    }
    kint[node_base + nb + tid] = bi;
    rs[node_base + nb + tid] = (float)bi;
  }
}

// ---------------- gather-sum of kept neighbors ----------------
__global__ void gather_kernel(const float* __restrict__ feat, const int* __restrict__ nn,
                              const int* __restrict__ kint, float* __restrict__ out) {
  int idx = blockIdx.x * 256 + threadIdx.x;
  int node = idx / 24, c4 = idx % 24;
  int kc = kint[node];
  const int* nr = nn + (size_t)node * KNN;
  float4 acc = make_float4(0.f, 0.f, 0.f, 0.f);
  for (int k = 0; k < kc; k++) {
    int j = nr[k];
    float4 v = ((const float4*)(feat + (size_t)j * C))[c4];
    acc.x += v.x; acc.y += v.y; acc.z += v.z; acc.w += v.w;
  }
  ((float4*)(out + (size_t)node * C))[c4] = acc;
}

// ---------------- generic fp32 GEMM ----------------
// C[M,N] = [A0 (rowscale sc0) | A1 (rowscale sc1)] @ B' + bscale*bias, opt relu,
// opt transpose-store to [B, COUT, NPB]. bmode 1: B' rows k<96 are B[k]-B[k+96].
__global__ __launch_bounds__(256) void gemm_kernel(
    const float* __restrict__ A0, const float* __restrict__ A1, int K0, int Ktot,
    const float* __restrict__ sc0, const float* __restrict__ sc1,
    const float* __restrict__ B, int ldb, int bmode,
    const float* __restrict__ bias, const float* __restrict__ bscale,
    float* __restrict__ Cc, int M, int N, int relu, int tstore) {
  __shared__ float As[16][68];
  __shared__ float Bs[16][68];
  int tid = threadIdx.x;
  int tx = tid & 15, ty = tid >> 4;
  int row0 = blockIdx.x * 64, col0 = blockIdx.y * 64;
  float acc[4][4] = {};
  int ai = tid >> 2;          // 0..63
  int ak = (tid & 3) * 4;     // 0,4,8,12
  int bk = tid >> 4;          // 0..15
  int bj = (tid & 15) * 4;    // 0..60
  bool edge = (col0 + 64 > N);

  for (int k0 = 0; k0 < Ktot; k0 += 16) {
    {
      const float* Ap;
      const float* sc;
      int lda, kk;
      if (k0 < K0) { Ap = A0; lda = K0; sc = sc0; kk = k0; }
      else { Ap = A1; lda = Ktot - K0; sc = sc1; kk = k0 - K0; }
      int r = row0 + ai;
      float4 v = *(const float4*)(Ap + (size_t)r * lda + kk + ak);
      if (sc) { float s = sc[r]; v.x *= s; v.y *= s; v.z *= s; v.w *= s; }
      As[ak + 0][ai] = v.x;
      As[ak + 1][ai] = v.y;
      As[ak + 2][ai] = v.z;
      As[ak + 3][ai] = v.w;
    }
    {
      int kg = k0 + bk;
      int j = col0 + bj;
      float4 v;
      if (!edge) {
        v = *(const float4*)(B + (size_t)kg * ldb + j);
        if (bmode == 1 && kg < 96) {
          float4 w = *(const float4*)(B + (size_t)(kg + 96) * ldb + j);
          v.x -= w.x; v.y -= w.y; v.z -= w.z; v.w -= w.w;
        }
      } else {
        float tmp[4];
#pragma unroll
        for (int e = 0; e < 4; e++) {
          int jj = j + e;
          float val = 0.f;
          if (jj < N) {
            val = B[(size_t)kg * ldb + jj];
            if (bmode == 1 && kg < 96) val -= B[(size_t)(kg + 96) * ldb + jj];
          }
          tmp[e] = val;
        }
        v = make_float4(tmp[0], tmp[1], tmp[2], tmp[3]);
      }
      *(float4*)&Bs[bk][bj] = v;
    }
    __syncthreads();
#pragma unroll
    for (int kk = 0; kk < 16; kk++) {
      float4 av = *(const float4*)&As[kk][ty * 4];
      float4 bv = *(const float4*)&Bs[kk][tx * 4];
      acc[0][0] += av.x * bv.x; acc[0][1] += av.x * bv.y; acc[0][2] += av.x * bv.z; acc[0][3] += av.x * bv.w;
      acc[1][0] += av.y * bv.x; acc[1][1] += av.y * bv.y; acc[1][2] += av.y * bv.z; acc[1][3] += av.y * bv.w;
      acc[2][0] += av.z * bv.x; acc[2][1] += av.z * bv.y; acc[2][2] += av.z * bv.z; acc[2][3] += av.z * bv.w;
      acc[3][0] += av.w * bv.x; acc[3][1] += av.w * bv.y; acc[3][2] += av.w * bv.z; acc[3][3] += av.w * bv.w;
    }
    __syncthreads();
  }
#pragma unroll
  for (int ii = 0; ii < 4; ii++) {
    int r = row0 + ty * 4 + ii;
    float bsv = bscale ? bscale[r] : 1.f;
#pragma unroll
    for (int jj = 0; jj < 4; jj++) {
      int j = col0 + tx * 4 + jj;
      if (edge && j >= N) continue;
      float v = acc[ii][jj];
      if (bias) v += bsv * bias[j];
      if (relu) v = fmaxf(v, 0.f);
      if (tstore) {
        int bb = r / NPB, n = r % NPB;
        Cc[(size_t)bb * COUT * NPB + (size_t)j * NPB + n] = v;
      } else {
        Cc[(size_t)r * N + j] = v;
      }
    }
  }
}

extern "C" void kernel_launch(void* const* d_in, const int* in_sizes, int n_in,
                              void* d_out, int out_size, void* d_ws, size_t ws_size,
                              hipStream_t stream) {
  const float* x      = (const float*)d_in[0];
  const float* kmap_w = (const float*)d_in[1];
  const float* kmap_b = (const float*)d_in[2];
  const float* kfc_w  = (const float*)d_in[3];
  const float* kfc_b  = (const float*)d_in[4];
  const float* kmu_w  = (const float*)d_in[5];
  const float* kmu_b  = (const float*)d_in[6];
  const float* kdec_w = (const float*)d_in[7];
  const float* kdec_b = (const float*)d_in[8];
  const float* ec1_w  = (const float*)d_in[9];
  const float* ec1_b  = (const float*)d_in[10];
  const float* ec2_w  = (const float*)d_in[11];
  const float* ec2_b  = (const float*)d_in[12];
  const float* fc_w   = (const float*)d_in[13];
  const float* fc_b   = (const float*)d_in[14];
  const float* io_w   = (const float*)d_in[15];
  const float* io_b   = (const float*)d_in[16];
  const float* up_w   = (const float*)d_in[17];
  const float* up_b   = (const float*)d_in[18];

  // ---- workspace layout (liveness-aliased; total ~49.4 MB) ----
  char* ws = (char*)d_ws;
  size_t off = 0;
  auto alloc = [&](size_t bytes) -> void* {
    void* p = ws + off;
    off += (bytes + 255) & ~(size_t)255;
    return p;
  };
  float* xf    = (float*)alloc((size_t)NODES * C * 4);   // later reused as bufH2
  float* sqb   = (float*)alloc((size_t)NODES * 4);
  float* rs    = (float*)alloc((size_t)NODES * 4);
  int*   kint  = (int*)alloc((size_t)NODES * 4);
  int*   nn    = (int*)alloc((size_t)NODES * KNN * 4);
  float* bufH1 = (float*)alloc((size_t)NODES * C * 4);   // NODES*C*4 is 256-aligned
  float* bufS  = (float*)alloc((size_t)NODES * C * 4);   // contiguous after bufH1
  float* bufXio = (float*)alloc((size_t)NODES * COUT * 4);
  float* hK     = bufXio;  // VAE intermediate; dead before knn filter writes pk_i
  int*   pk_i   = (int*)bufXio;  // NODES*24 ints = 2.4 MB; dead before xio GEMM
  unsigned short* xh = (unsigned short*)bufH1;  // bf16 hi; dead before h1 GEMM writes
  unsigned short* xl = (unsigned short*)bufS;   // bf16 lo; dead before gather1 writes
  float* bufH2  = xf;      // xf dead after xio GEMM
  float* bufAgg = bufH1;   // spans bufH1+bufS (exactly NODES*COUT*4); both dead

  transpose_kernel<<<dim3(98, 3, 8), dim3(32, 8), 0, stream>>>(x, xf);
  sq_kernel<<<98, 256, 0, stream>>>(xf, sqb);
  split_kernel<<<2352, 256, 0, stream>>>(xf, xh, xl);

  // VAE head: 96->500 GEMM (M-chunked, uses hK alias) + fused tail -> k_int
  for (int c = 0; c < 4; c++) {
    gemm_kernel<<<dim3(98, 8), 256, 0, stream>>>(
        xf + (size_t)c * 6272 * C, nullptr, 96, 96, nullptr, nullptr,
        kmap_w, 500, 0, kmap_b, nullptr, hK, 6272, 500, 0, 0);
    vae_tail_kernel<<<784, 256, 0, stream>>>(hK, kfc_w, kfc_b, kmu_w, kmu_b,
                                             kdec_w, kdec_b, c * 6272, kint, rs);
  }

  // kNN: MFMA split-bf16 filter (top-12 per half) + exact fp32 rescore -> top-9
  knn_mfma_kernel<<<dim3(49, 8, MSPLIT), 256, 0, stream>>>(xh, xl, sqb, pk_i);
  rescore_kernel<<<98, 256, 0, stream>>>(xf, sqb, pk_i, nn);

  // EdgeConv layer 1: h1 = relu(k*xi@(W1-W2) + S@W2 + k*b)
  gather_kernel<<<2352, 256, 0, stream>>>(xf, nn, kint, bufS);
  gemm_kernel<<<dim3(392, 2), 256, 0, stream>>>(
      xf, bufS, 96, 192, rs, nullptr, ec1_w, 96, 1, ec1_b, rs, bufH1, NODES, 96, 1, 0);

  // xio = nodes @ io_w + io_b  (overwrites bufXio; pk_i dead)
  gemm_kernel<<<dim3(392, 3), 256, 0, stream>>>(
      xf, nullptr, 96, 96, nullptr, nullptr, io_w, COUT, 0, io_b, nullptr, bufXio, NODES, COUT, 0, 0);

  // EdgeConv layer 2 (no relu); output aliases xf (dead after xio GEMM)
  gather_kernel<<<2352, 256, 0, stream>>>(bufH1, nn, kint, bufS);
  gemm_kernel<<<dim3(392, 2), 256, 0, stream>>>(
      bufH1, bufS, 96, 192, rs, nullptr, ec2_w, 96, 1, ec2_b, rs, bufH2, NODES, 96, 0, 0);

  // agg = h2 @ fc_w + fc_b (aliases bufH1+bufS, both dead)
  gemm_kernel<<<dim3(392, 3), 256, 0, stream>>>(
      bufH2, nullptr, 96, 96, nullptr, nullptr, fc_w, COUT, 0, fc_b, nullptr, bufAgg, NODES, COUT, 0, 0);

  // final: relu([xio | agg] @ up_w + up_b), transpose-store to [B, 192, 3136]
  gemm_kernel<<<dim3(392, 3), 256, 0, stream>>>(
      bufXio, bufAgg, 192, 384, nullptr, nullptr, up_w, COUT, 0, up_b, nullptr,
      (float*)d_out, NODES, COUT, 1, 1);
}

// Round 9
// 756.764 us; speedup vs baseline: 1.6643x; 1.1648x over previous
//
#include <hip/hip_runtime.h>

#define NODES 25088
#define NB 8
#define NPB 3136   // nodes per batch (56*56)
#define C 96
#define KNN 9
#define COUT 192
#define MSPLIT 4   // m-range quarters for knn filter
#define T12 12     // filter depth per quarter (>= 10 guarantees exact top-9 coverage)
#define NCAND (MSPLIT * T12)  // 48 rescore candidates per query

typedef float f32x4 __attribute__((ext_vector_type(4)));
typedef float f32x16 __attribute__((ext_vector_type(16)));
typedef short s16x8 __attribute__((ext_vector_type(8)));

__device__ __forceinline__ unsigned short f2bf(float x) {
  unsigned u = __float_as_uint(x);
  return (unsigned short)((u + 0x7fffu + ((u >> 16) & 1u)) >> 16);
}
__device__ __forceinline__ float bf2f(unsigned short h) {
  return __uint_as_float(((unsigned)h) << 16);
}

// ---------------- transpose x [B,C,N] -> xf [B*N, C] ----------------
__global__ void transpose_kernel(const float* __restrict__ x, float* __restrict__ xf) {
  __shared__ float t[32][33];
  int b = blockIdx.z, ct = blockIdx.y, nt = blockIdx.x;
  int tx = threadIdx.x, ty = threadIdx.y;
  int n0 = nt * 32, c0 = ct * 32;
  const float* xb = x + (size_t)b * C * NPB;
#pragma unroll
  for (int i = 0; i < 4; i++) {
    int c = c0 + ty + i * 8;
    t[ty + i * 8][tx] = xb[(size_t)c * NPB + n0 + tx];
  }
  __syncthreads();
  float* xfb = xf + (size_t)b * NPB * C;
#pragma unroll
  for (int i = 0; i < 4; i++) {
    int n = n0 + ty + i * 8;
    xfb[(size_t)n * C + c0 + tx] = t[tx][ty + i * 8];
  }
}

// ---------------- per-node squared norm ----------------
__global__ void sq_kernel(const float* __restrict__ xf, float* __restrict__ sq) {
  int node = blockIdx.x * 256 + threadIdx.x;
  const float4* r = (const float4*)(xf + (size_t)node * C);
  float s = 0.f;
#pragma unroll
  for (int i = 0; i < 24; i++) {
    float4 v = r[i];
    s += v.x * v.x + v.y * v.y + v.z * v.z + v.w * v.w;
  }
  sq[node] = s;
}

// ---------------- fp32 -> bf16 hi/lo split ----------------
__global__ void split_kernel(const float* __restrict__ xf,
                             unsigned short* __restrict__ xh,
                             unsigned short* __restrict__ xl) {
  int i = blockIdx.x * 256 + threadIdx.x;  // one float4 per thread
  float4 v = ((const float4*)xf)[i];
  ushort4 h, l;
  h.x = f2bf(v.x); l.x = f2bf(v.x - bf2f(h.x));
  h.y = f2bf(v.y); l.y = f2bf(v.y - bf2f(h.y));
  h.z = f2bf(v.z); l.z = f2bf(v.z - bf2f(h.z));
  h.w = f2bf(v.w); l.w = f2bf(v.w - bf2f(h.w));
  ((ushort4*)xh)[i] = h;
  ((ushort4*)xl)[i] = l;
}

// ---------------- MFMA kNN filter: approx top-12 per m-quarter per query ----------------
// grid (49, 8, MSPLIT), block 256 (4 waves). Block: 64 queries x quarter m-range.
// One-sided split: S ~= (ah+al)*bh (B bf16-hi only, dot err sigma ~0.03).
// Selection on packed keys: d with low-10 mantissa bits = quarter-local m index;
// branchless sorted insert (12x fmin/fmax). Transposed S store (4 b128/wave).
__global__ __launch_bounds__(256) void knn_mfma_kernel(
    const unsigned short* __restrict__ xh, const unsigned short* __restrict__ xl,
    const float* __restrict__ sq, int* __restrict__ pk_i) {
  __shared__ unsigned short mh[64 * 104];   // 13312 B (bf16-hi m-tile)
  __shared__ float ST[64 * 68];             // 17408 B (S transposed: [m][q])
  __shared__ float sqs[64];
  int tid = threadIdx.x;
  int lane = tid & 63, wv = tid >> 6;
  int b = blockIdx.y, z = blockIdx.z;
  int q0 = blockIdx.x * 64;
  int bbase = b * NPB;
  int t0 = (z * 49) / MSPLIT, t1 = ((z + 1) * 49) / MSPLIT;

  // A-fragments: wave's 32 queries, fixed across tiles. A[m=lane&31][k=(lane>>5)*8+j]
  int koff = (lane >> 5) * 8;
  int rowA = bbase + q0 + (wv >> 1) * 32 + (lane & 31);
  s16x8 ah[6], al[6];
  {
    const unsigned short* ph = xh + (size_t)rowA * 96 + koff;
    const unsigned short* pl = xl + (size_t)rowA * 96 + koff;
#pragma unroll
    for (int kc = 0; kc < 6; kc++) {
      ah[kc] = *(const s16x8*)(ph + kc * 16);
      al[kc] = *(const s16x8*)(pl + kc * 16);
    }
  }
  float sqr = sq[bbase + q0 + lane];  // scan role: lane = query

  float fd[T12];
#pragma unroll
  for (int k = 0; k < T12; k++) fd[k] = 3.4e38f;

  int srow = tid >> 2, sseg = tid & 3;  // staging: 4 threads per row, 3 segs each

  for (int t = t0; t < t1; t++) {
    int m0 = t * 64;
    __syncthreads();
    {
      const unsigned short* gh = xh + (size_t)(bbase + m0 + srow) * 96;
#pragma unroll
      for (int i = 0; i < 3; i++) {
        int s = sseg * 3 + i;
        *(s16x8*)(mh + srow * 104 + s * 8) = *(const s16x8*)(gh + s * 8);
      }
      if (tid < 64) sqs[tid] = sq[bbase + m0 + tid];
    }
    __syncthreads();

    // B-fragments for this wave's m-quadrant: B[k=(lane>>5)*8+j][n=lane&31]
    int mrow = (wv & 1) * 32 + (lane & 31);
    s16x8 bh[6];
#pragma unroll
    for (int kc = 0; kc < 6; kc++)
      bh[kc] = *(const s16x8*)(mh + mrow * 104 + kc * 16 + koff);

    f32x16 acc = (f32x16){0.f, 0.f, 0.f, 0.f, 0.f, 0.f, 0.f, 0.f,
                          0.f, 0.f, 0.f, 0.f, 0.f, 0.f, 0.f, 0.f};
    asm volatile(
        "s_nop 1\n\t"
        "v_mfma_f32_32x32x16_bf16 %0, %1, %13, %0\n\t"
        "v_mfma_f32_32x32x16_bf16 %0, %7, %13, %0\n\t"
        "v_mfma_f32_32x32x16_bf16 %0, %2, %14, %0\n\t"
        "v_mfma_f32_32x32x16_bf16 %0, %8, %14, %0\n\t"
        "v_mfma_f32_32x32x16_bf16 %0, %3, %15, %0\n\t"
        "v_mfma_f32_32x32x16_bf16 %0, %9, %15, %0\n\t"
        "v_mfma_f32_32x32x16_bf16 %0, %4, %16, %0\n\t"
        "v_mfma_f32_32x32x16_bf16 %0, %10, %16, %0\n\t"
        "v_mfma_f32_32x32x16_bf16 %0, %5, %17, %0\n\t"
        "v_mfma_f32_32x32x16_bf16 %0, %11, %17, %0\n\t"
        "v_mfma_f32_32x32x16_bf16 %0, %6, %18, %0\n\t"
        "v_mfma_f32_32x32x16_bf16 %0, %12, %18, %0\n\t"
        "s_nop 7\n\t"
        "s_nop 7\n\t"
        "s_nop 7"
        : "+v"(acc)
        : "v"(ah[0]), "v"(ah[1]), "v"(ah[2]), "v"(ah[3]), "v"(ah[4]), "v"(ah[5]),
          "v"(al[0]), "v"(al[1]), "v"(al[2]), "v"(al[3]), "v"(al[4]), "v"(al[5]),
          "v"(bh[0]), "v"(bh[1]), "v"(bh[2]), "v"(bh[3]), "v"(bh[4]), "v"(bh[5]));

    // C/D 32x32: col=lane&31, row=(reg&3)+8*(reg>>2)+4*(lane>>5). Transposed store:
    // ST[m][q], addr = m*68 + q; regs 4g..4g+3 are 4 consecutive q -> b128.
    {
      int mcol = (wv & 1) * 32 + (lane & 31);
      int qbase = (wv >> 1) * 32 + 4 * (lane >> 5);
#pragma unroll
      for (int g = 0; g < 4; g++) {
        f32x4 v = (f32x4){acc[4 * g + 0], acc[4 * g + 1], acc[4 * g + 2], acc[4 * g + 3]};
        *(f32x4*)(ST + mcol * 68 + qbase + 8 * g) = v;
      }
    }
    __syncthreads();

    // scan: lane = query, wave wv scans m-strip [wv*16, wv*16+16)
    int lbase = (t - t0) * 64;  // quarter-local m index base (fits 10 bits)
#pragma unroll
    for (int i = 0; i < 16; i++) {
      int mloc = wv * 16 + i;
      float d = fmaf(-2.f, ST[mloc * 68 + lane], sqr + sqs[mloc]);
      unsigned u = (__float_as_uint(d) & 0xFFFFFC00u) | (unsigned)(lbase + mloc);
      float key = __uint_as_float(u);
      if (key < fd[T12 - 1]) {
        float t2 = key;
#pragma unroll
        for (int k = 0; k < T12; k++) {
          float lo = fminf(fd[k], t2);
          t2 = fmaxf(fd[k], t2);
          fd[k] = lo;
        }
      }
    }
  }

  // merge the 4 wave-strips (per query) via LDS; key list aliases dead mh
  __syncthreads();
  float* cd = (float*)mh;  // 4*64*12 floats = 12288 B <= 13312
#pragma unroll
  for (int k = 0; k < T12; k++) cd[(wv * 64 + lane) * T12 + k] = fd[k];
  __syncthreads();
  if (wv == 0) {
    float gd[T12];
#pragma unroll
    for (int k = 0; k < T12; k++) gd[k] = 3.4e38f;
    for (int s = 0; s < 4; s++) {
#pragma unroll
      for (int k = 0; k < T12; k++) {
        float key = cd[(s * 64 + lane) * T12 + k];
        if (key < gd[T12 - 1]) {
          float t2 = key;
#pragma unroll
          for (int kk = 0; kk < T12; kk++) {
            float lo = fminf(gd[kk], t2);
            t2 = fmaxf(gd[kk], t2);
            gd[kk] = lo;
          }
        }
      }
    }
    size_t base = ((size_t)(bbase + q0 + lane) * MSPLIT + z) * T12;
#pragma unroll
    for (int k = 0; k < T12; k++) {
      int mloc = (int)(__float_as_uint(gd[k]) & 0x3FFu) + t0 * 64;
      pk_i[base + k] = bbase + mloc;
    }
  }
}

// ---------------- exact fp32 rescore of NCAND candidates -> top-9 ----------------
// block 256 = 4 queries x 64 lanes; lane c < NCAND computes one exact dot.
__global__ void rescore_kernel(const float* __restrict__ xf, const float* __restrict__ sq,
                               const int* __restrict__ pk_i, int* __restrict__ nn) {
  __shared__ float qr[4][96];
  __shared__ float sqq[4];
  __shared__ float dd[4][NCAND];
  __shared__ int jj[4][NCAND];
  int tid = threadIdx.x;
  int qloc = tid >> 6, c = tid & 63;
  int qbase = blockIdx.x * 4;
  // stage 4 query rows + norms (384 floats, 256 threads -> strided loop; R8 bug fix)
  for (int f = tid; f < 4 * 96; f += 256)
    qr[f / 96][f % 96] = xf[(size_t)(qbase + f / 96) * 96 + f % 96];
  if (tid < 4) sqq[tid] = sq[qbase + tid];
  __syncthreads();
  if (c < NCAND) {
    int q = qbase + qloc;
    int j = pk_i[(size_t)q * NCAND + c];
    const float4* qp = (const float4*)qr[qloc];
    const float4* mp = (const float4*)(xf + (size_t)j * 96);
    float d0 = 0.f, d1 = 0.f, d2 = 0.f, d3 = 0.f;
#pragma unroll
    for (int i = 0; i < 24; i++) {
      float4 qv = qp[i];
      float4 mv = mp[i];
      d0 += qv.x * mv.x;
      d1 += qv.y * mv.y;
      d2 += qv.z * mv.z;
      d3 += qv.w * mv.w;
    }
    dd[qloc][c] = (sqq[qloc] - 2.0f * ((d0 + d1) + (d2 + d3))) + sq[j];
    jj[qloc][c] = j;
  }
  __syncthreads();
  if (c == 0) {
    int q = qbase + qloc;
    float fd[KNN];
    int fi[KNN];
#pragma unroll
    for (int k = 0; k < KNN; k++) { fd[k] = 3.4e38f; fi[k] = 0x7fffffff; }
    for (int e = 0; e < NCAND; e++) {
      float d = dd[qloc][e];
      int j = jj[qloc][e];
      if (d < fd[KNN - 1] || (d == fd[KNN - 1] && j < fi[KNN - 1])) {
        fd[KNN - 1] = d;
        fi[KNN - 1] = j;
#pragma unroll
        for (int k = KNN - 1; k > 0; --k) {
          bool sw = (fd[k] < fd[k - 1]) || (fd[k] == fd[k - 1] && fi[k] < fi[k - 1]);
          if (sw) {
            float td = fd[k]; fd[k] = fd[k - 1]; fd[k - 1] = td;
            int ti = fi[k]; fi[k] = fi[k - 1]; fi[k - 1] = ti;
          }
        }
      }
    }
#pragma unroll
    for (int k = 0; k < KNN; k++) nn[(size_t)q * KNN + k] = fi[k];
  }
}

// ---------------- fused VAE tail: hK[500] -> 64 -> 32 -> 9 -> argmax ----------------
__global__ void vae_tail_kernel(const float* __restrict__ hK,
                                const float* __restrict__ kfc_w, const float* __restrict__ kfc_b,
                                const float* __restrict__ kmu_w, const float* __restrict__ kmu_b,
                                const float* __restrict__ kdec_w, const float* __restrict__ kdec_b,
                                int node_base, int* __restrict__ kint, float* __restrict__ rs) {
  __shared__ float hrow[8][500];
  __shared__ float h64s[8][64];
  __shared__ float mus[8][32];
  __shared__ float lg[8][9];
  int tid = threadIdx.x;
  int nb = blockIdx.x * 8;
  for (int f = tid; f < 8 * 500; f += 256) {
    int nl = f / 500, q = f % 500;
    hrow[nl][q] = hK[(size_t)(nb + nl) * 500 + q];
  }
  __syncthreads();
  {
    int nl0 = tid >> 6, j = tid & 63;
    float a0 = 0.f, a1 = 0.f;
    for (int q = 0; q < 500; q++) {
      float w = kfc_w[q * 64 + j];
      a0 += hrow[nl0][q] * w;
      a1 += hrow[nl0 + 4][q] * w;
    }
    float bj = kfc_b[j];
    h64s[nl0][j] = fmaxf(a0 + bj, 0.f);
    h64s[nl0 + 4][j] = fmaxf(a1 + bj, 0.f);
  }
  __syncthreads();
  {
    int nl = tid / 32, j = tid % 32;
    float a = 0.f;
#pragma unroll
    for (int q = 0; q < 64; q++) a += h64s[nl][q] * kmu_w[q * 32 + j];
    mus[nl][j] = a + kmu_b[j];
  }
  __syncthreads();
  if (tid < 72) {
    int nl = tid / 9, j = tid % 9;
    float a = 0.f;
#pragma unroll
    for (int q = 0; q < 32; q++) a += mus[nl][q] * kdec_w[q * 9 + j];
    lg[nl][j] = a + kdec_b[j];
  }
  __syncthreads();
  if (tid < 8) {
    float best = lg[tid][0];
    int bi = 0;
#pragma unroll
    for (int j = 1; j < 9; j++) {
      if (lg[tid][j] > best) { best = lg[tid][j]; bi = j; }
    }
    kint[node_base + nb + tid] = bi;
    rs[node_base + nb + tid] = (float)bi;
  }
}

// ---------------- gather-sum of kept neighbors ----------------
__global__ void gather_kernel(const float* __restrict__ feat, const int* __restrict__ nn,
                              const int* __restrict__ kint, float* __restrict__ out) {
  int idx = blockIdx.x * 256 + threadIdx.x;
  int node = idx / 24, c4 = idx % 24;
  int kc = kint[node];
  const int* nr = nn + (size_t)node * KNN;
  float4 acc = make_float4(0.f, 0.f, 0.f, 0.f);
  for (int k = 0; k < kc; k++) {
    int j = nr[k];
    float4 v = ((const float4*)(feat + (size_t)j * C))[c4];
    acc.x += v.x; acc.y += v.y; acc.z += v.z; acc.w += v.w;
  }
  ((float4*)(out + (size_t)node * C))[c4] = acc;
}

// ---------------- generic fp32 GEMM ----------------
__global__ __launch_bounds__(256) void gemm_kernel(
    const float* __restrict__ A0, const float* __restrict__ A1, int K0, int Ktot,
    const float* __restrict__ sc0, const float* __restrict__ sc1,
    const float* __restrict__ B, int ldb, int bmode,
    const float* __restrict__ bias, const float* __restrict__ bscale,
    float* __restrict__ Cc, int M, int N, int relu, int tstore) {
  __shared__ float As[16][68];
  __shared__ float Bs[16][68];
  int tid = threadIdx.x;
  int tx = tid & 15, ty = tid >> 4;
  int row0 = blockIdx.x * 64, col0 = blockIdx.y * 64;
  float acc[4][4] = {};
  int ai = tid >> 2;
  int ak = (tid & 3) * 4;
  int bk = tid >> 4;
  int bj = (tid & 15) * 4;
  bool edge = (col0 + 64 > N);

  for (int k0 = 0; k0 < Ktot; k0 += 16) {
    {
      const float* Ap;
      const float* sc;
      int lda, kk;
      if (k0 < K0) { Ap = A0; lda = K0; sc = sc0; kk = k0; }
      else { Ap = A1; lda = Ktot - K0; sc = sc1; kk = k0 - K0; }
      int r = row0 + ai;
      float4 v = *(const float4*)(Ap + (size_t)r * lda + kk + ak);
      if (sc) { float s = sc[r]; v.x *= s; v.y *= s; v.z *= s; v.w *= s; }
      As[ak + 0][ai] = v.x;
      As[ak + 1][ai] = v.y;
      As[ak + 2][ai] = v.z;
      As[ak + 3][ai] = v.w;
    }
    {
      int kg = k0 + bk;
      int j = col0 + bj;
      float4 v;
      if (!edge) {
        v = *(const float4*)(B + (size_t)kg * ldb + j);
        if (bmode == 1 && kg < 96) {
          float4 w = *(const float4*)(B + (size_t)(kg + 96) * ldb + j);
          v.x -= w.x; v.y -= w.y; v.z -= w.z; v.w -= w.w;
        }
      } else {
        float tmp[4];
#pragma unroll
        for (int e = 0; e < 4; e++) {
          int jjx = j + e;
          float val = 0.f;
          if (jjx < N) {
            val = B[(size_t)kg * ldb + jjx];
            if (bmode == 1 && kg < 96) val -= B[(size_t)(kg + 96) * ldb + jjx];
          }
          tmp[e] = val;
        }
        v = make_float4(tmp[0], tmp[1], tmp[2], tmp[3]);
      }
      *(float4*)&Bs[bk][bj] = v;
    }
    __syncthreads();
#pragma unroll
    for (int kk = 0; kk < 16; kk++) {
      float4 av = *(const float4*)&As[kk][ty * 4];
      float4 bv = *(const float4*)&Bs[kk][tx * 4];
      acc[0][0] += av.x * bv.x; acc[0][1] += av.x * bv.y; acc[0][2] += av.x * bv.z; acc[0][3] += av.x * bv.w;
      acc[1][0] += av.y * bv.x; acc[1][1] += av.y * bv.y; acc[1][2] += av.y * bv.z; acc[1][3] += av.y * bv.w;
      acc[2][0] += av.z * bv.x; acc[2][1] += av.z * bv.y; acc[2][2] += av.z * bv.z; acc[2][3] += av.z * bv.w;
      acc[3][0] += av.w * bv.x; acc[3][1] += av.w * bv.y; acc[3][2] += av.w * bv.z; acc[3][3] += av.w * bv.w;
    }
    __syncthreads();
  }
#pragma unroll
  for (int ii = 0; ii < 4; ii++) {
    int r = row0 + ty * 4 + ii;
    float bsv = bscale ? bscale[r] : 1.f;
#pragma unroll
    for (int jjx = 0; jjx < 4; jjx++) {
      int j = col0 + tx * 4 + jjx;
      if (edge && j >= N) continue;
      float v = acc[ii][jjx];
      if (bias) v += bsv * bias[j];
      if (relu) v = fmaxf(v, 0.f);
      if (tstore) {
        int bb = r / NPB, n = r % NPB;
        Cc[(size_t)bb * COUT * NPB + (size_t)j * NPB + n] = v;
      } else {
        Cc[(size_t)r * N + j] = v;
      }
    }
  }
}

extern "C" void kernel_launch(void* const* d_in, const int* in_sizes, int n_in,
                              void* d_out, int out_size, void* d_ws, size_t ws_size,
                              hipStream_t stream) {
  const float* x      = (const float*)d_in[0];
  const float* kmap_w = (const float*)d_in[1];
  const float* kmap_b = (const float*)d_in[2];
  const float* kfc_w  = (const float*)d_in[3];
  const float* kfc_b  = (const float*)d_in[4];
  const float* kmu_w  = (const float*)d_in[5];
  const float* kmu_b  = (const float*)d_in[6];
  const float* kdec_w = (const float*)d_in[7];
  const float* kdec_b = (const float*)d_in[8];
  const float* ec1_w  = (const float*)d_in[9];
  const float* ec1_b  = (const float*)d_in[10];
  const float* ec2_w  = (const float*)d_in[11];
  const float* ec2_b  = (const float*)d_in[12];
  const float* fc_w   = (const float*)d_in[13];
  const float* fc_b   = (const float*)d_in[14];
  const float* io_w   = (const float*)d_in[15];
  const float* io_b   = (const float*)d_in[16];
  const float* up_w   = (const float*)d_in[17];
  const float* up_b   = (const float*)d_in[18];

  // ---- workspace layout (liveness-aliased; total ~49.4 MB) ----
  char* ws = (char*)d_ws;
  size_t off = 0;
  auto alloc = [&](size_t bytes) -> void* {
    void* p = ws + off;
    off += (bytes + 255) & ~(size_t)255;
    return p;
  };
  float* xf    = (float*)alloc((size_t)NODES * C * 4);   // later reused as bufH2
  float* sqb   = (float*)alloc((size_t)NODES * 4);
  float* rs    = (float*)alloc((size_t)NODES * 4);
  int*   kint  = (int*)alloc((size_t)NODES * 4);
  int*   nn    = (int*)alloc((size_t)NODES * KNN * 4);
  float* bufH1 = (float*)alloc((size_t)NODES * C * 4);   // NODES*C*4 is 256-aligned
  float* bufS  = (float*)alloc((size_t)NODES * C * 4);   // contiguous after bufH1
  float* bufXio = (float*)alloc((size_t)NODES * COUT * 4);
  float* hK     = bufXio;  // VAE intermediate; dead before knn filter writes pk_i
  int*   pk_i   = (int*)bufXio;  // NODES*48 ints = 4.8 MB; dead before xio GEMM
  unsigned short* xh = (unsigned short*)bufH1;  // bf16 hi; dead before h1 GEMM writes
  unsigned short* xl = (unsigned short*)bufS;   // bf16 lo; dead before gather1 writes
  float* bufH2  = xf;      // xf dead after xio GEMM
  float* bufAgg = bufH1;   // spans bufH1+bufS (exactly NODES*COUT*4); both dead

  transpose_kernel<<<dim3(98, 3, 8), dim3(32, 8), 0, stream>>>(x, xf);
  sq_kernel<<<98, 256, 0, stream>>>(xf, sqb);
  split_kernel<<<2352, 256, 0, stream>>>(xf, xh, xl);

  // VAE head: 96->500 GEMM (M-chunked, uses hK alias) + fused tail -> k_int
  for (int c = 0; c < 4; c++) {
    gemm_kernel<<<dim3(98, 8), 256, 0, stream>>>(
        xf + (size_t)c * 6272 * C, nullptr, 96, 96, nullptr, nullptr,
        kmap_w, 500, 0, kmap_b, nullptr, hK, 6272, 500, 0, 0);
    vae_tail_kernel<<<784, 256, 0, stream>>>(hK, kfc_w, kfc_b, kmu_w, kmu_b,
                                             kdec_w, kdec_b, c * 6272, kint, rs);
  }

  // kNN: MFMA filter (top-12 per quarter, packed keys) + exact fp32 rescore -> top-9
  knn_mfma_kernel<<<dim3(49, 8, MSPLIT), 256, 0, stream>>>(xh, xl, sqb, pk_i);
  rescore_kernel<<<6272, 256, 0, stream>>>(xf, sqb, pk_i, nn);

  // EdgeConv layer 1: h1 = relu(k*xi@(W1-W2) + S@W2 + k*b)
  gather_kernel<<<2352, 256, 0, stream>>>(xf, nn, kint, bufS);
  gemm_kernel<<<dim3(392, 2), 256, 0, stream>>>(
      xf, bufS, 96, 192, rs, nullptr, ec1_w, 96, 1, ec1_b, rs, bufH1, NODES, 96, 1, 0);

  // xio = nodes @ io_w + io_b  (overwrites bufXio; pk_i dead)
  gemm_kernel<<<dim3(392, 3), 256, 0, stream>>>(
      xf, nullptr, 96, 96, nullptr, nullptr, io_w, COUT, 0, io_b, nullptr, bufXio, NODES, COUT, 0, 0);

  // EdgeConv layer 2 (no relu); output aliases xf (dead after xio GEMM)
  gather_kernel<<<2352, 256, 0, stream>>>(bufH1, nn, kint, bufS);
  gemm_kernel<<<dim3(392, 2), 256, 0, stream>>>(
      bufH1, bufS, 96, 192, rs, nullptr, ec2_w, 96, 1, ec2_b, rs, bufH2, NODES, 96, 0, 0);

  // agg = h2 @ fc_w + fc_b (aliases bufH1+bufS, both dead)
  gemm_kernel<<<dim3(392, 3), 256, 0, stream>>>(
      bufH2, nullptr, 96, 96, nullptr, nullptr, fc_w, COUT, 0, fc_b, nullptr, bufAgg, NODES, COUT, 0, 0);

  // final: relu([xio | agg] @ up_w + up_b), transpose-store to [B, 192, 3136]
  gemm_kernel<<<dim3(392, 3), 256, 0, stream>>>(
      bufXio, bufAgg, 192, 384, nullptr, nullptr, up_w, COUT, 0, up_b, nullptr,
      (float*)d_out, NODES, COUT, 1, 1);
}